// Round 17
// baseline (506.027 us; speedup 1.0000x reference)
//
#include <hip/hip_runtime.h>
#include <hip/hip_bf16.h>
#include <hip/hip_fp8.h>

#define NC 8192
#define NF 16384
#define NE 262144
#define TPAIR 16000  // bytes per node-pair: 125 kerns * 128 B
#define GB 8
#define NCELL 512
#define CELLH 0.125f

typedef __attribute__((ext_vector_type(8))) short short8v;  // 8 bf16
typedef __attribute__((ext_vector_type(4))) float f32x4;

// ---------------- binning: histogram over coarse points ----------------
__global__ __launch_bounds__(256) void bin_hist_kernel(
    const float* __restrict__ pos, int* __restrict__ cellCnt, int* __restrict__ cellId)
{
    const int i = blockIdx.x * 256 + threadIdx.x;
    const int cx = min((int)(pos[i*3+0] * GB), GB-1);
    const int cy = min((int)(pos[i*3+1] * GB), GB-1);
    const int cz = min((int)(pos[i*3+2] * GB), GB-1);
    const int cell = (cz*GB + cy)*GB + cx;
    cellId[i] = cell;
    atomicAdd(&cellCnt[cell], 1);
}

// ---------------- binning: scan 512 cells (writes sentinel) ----------------
__global__ __launch_bounds__(512) void bin_scan_kernel(
    const int* __restrict__ cellCnt, int* __restrict__ cellOffs, int* __restrict__ cellCursor)
{
    __shared__ int s[512];
    const int tid = threadIdx.x;
    const int v = cellCnt[tid];
    s[tid] = v;
    __syncthreads();
    for (int off = 1; off < 512; off <<= 1) {
        int t = (tid >= off) ? s[tid - off] : 0;
        __syncthreads();
        s[tid] += t;
        __syncthreads();
    }
    cellOffs[tid] = s[tid] - v;
    cellCursor[tid] = s[tid] - v;
    if (tid == 511) cellOffs[512] = s[511];
}

// ---------------- binning: scatter points -> packed float4 (xyz + batch bits) ----------------
__global__ __launch_bounds__(256) void bin_scatter_kernel(
    const float* __restrict__ pos, const int* __restrict__ batch,
    const int* __restrict__ cellId, int* __restrict__ cellCursor,
    int* __restrict__ binPts, float4* __restrict__ binPB)
{
    const int i = blockIdx.x * 256 + threadIdx.x;
    const int cell = cellId[i];
    const int p = atomicAdd(&cellCursor[cell], 1);
    binPts[p] = i;
    float4 q;
    q.x = pos[i*3+0]; q.y = pos[i*3+1]; q.z = pos[i*3+2];
    q.w = __int_as_float(batch[i]);
    binPB[p] = q;
}

// ---------------- KNN: one wave per query, 9 contiguous ranges, no LDS ----------------
__global__ __launch_bounds__(256) void knn_wave_kernel(
    const float4* __restrict__ binPB, const int* __restrict__ binPts,
    const int* __restrict__ cellOffs,
    const float* __restrict__ pos_skip, const int* __restrict__ batch_skip,
    int* __restrict__ idx3, float* __restrict__ w3, int* __restrict__ flags)
{
    const int lane = threadIdx.x & 63;
    const int y = blockIdx.x * 4 + (threadIdx.x >> 6);
    const float px = pos_skip[y*3+0], py = pos_skip[y*3+1], pz = pos_skip[y*3+2];
    const int by = batch_skip[y];
    const int cx = min((int)(px * GB), GB-1);
    const int cy = min((int)(py * GB), GB-1);
    const int cz = min((int)(pz * GB), GB-1);
    const int xlo = max(cx-1,0), xhi = min(cx+1,GB-1);
    const int ylo = max(cy-1,0), yhi = min(cy+1,GB-1);
    const int zlo = max(cz-1,0), zhi = min(cz+1,GB-1);

    float b0 = INFINITY, b1 = INFINITY, b2 = INFINITY;
    int i0 = 0, i1 = 0, i2 = 0;
    auto ins = [&](float d, int gj) {
        if (d < b2) {
            if (d < b1) {
                b2 = b1; i2 = i1;
                if (d < b0) { b1 = b0; i1 = i0; b0 = d; i0 = gj; }
                else        { b1 = d;  i1 = gj; }
            } else { b2 = d; i2 = gj; }
        }
    };

    for (int zz = zlo; zz <= zhi; ++zz)
    for (int yy = ylo; yy <= yhi; ++yy) {
        const int rowb = (zz*GB + yy)*GB;
        const int b = cellOffs[rowb + xlo];
        const int e = cellOffs[rowb + xhi + 1];
        for (int p = b + lane; p < e; p += 64) {
            const float4 q = binPB[p];
            const float dx = px - q.x, dy = py - q.y, dz = pz - q.z;
            float d = dx*dx + dy*dy + dz*dz;
            if (__float_as_int(q.w) != by) d = INFINITY;
            ins(d, binPts[p]);
        }
    }
    #pragma unroll
    for (int mask = 1; mask <= 32; mask <<= 1) {
        float c0 = __shfl_xor(b0, mask), c1 = __shfl_xor(b1, mask), c2 = __shfl_xor(b2, mask);
        int   j0 = __shfl_xor(i0, mask), j1 = __shfl_xor(i1, mask), j2 = __shfl_xor(i2, mask);
        ins(c0, j0); ins(c1, j1); ins(c2, j2);
    }
    if (lane == 0) {
        float rd = 1e30f;
        if (cx > 0)    rd = fminf(rd, px - (cx-1)*CELLH);
        if (cx < GB-1) rd = fminf(rd, (cx+2)*CELLH - px);
        if (cy > 0)    rd = fminf(rd, py - (cy-1)*CELLH);
        if (cy < GB-1) rd = fminf(rd, (cy+2)*CELLH - py);
        if (cz > 0)    rd = fminf(rd, pz - (cz-1)*CELLH);
        if (cz < GB-1) rd = fminf(rd, (cz+2)*CELLH - pz);
        if (!(b2 <= rd*rd)) flags[y] = 1;
        idx3[y*3+0] = i0; idx3[y*3+1] = i1; idx3[y*3+2] = i2;
        w3[y*3+0] = 1.0f / fmaxf(b0, 1e-16f);
        w3[y*3+1] = 1.0f / fmaxf(b1, 1e-16f);
        w3[y*3+2] = 1.0f / fmaxf(b2, 1e-16f);
    }
}

// ---------------- KNN fallback: exact brute force for flagged queries ----------------
__global__ __launch_bounds__(256) void knn_fallback_kernel(
    const float* __restrict__ pos, const int* __restrict__ batch,
    const float* __restrict__ pos_skip, const int* __restrict__ batch_skip,
    const int* __restrict__ flags, int* __restrict__ idx3, float* __restrict__ w3)
{
    const int s = threadIdx.x & 63;
    const int y = blockIdx.x * 4 + (threadIdx.x >> 6);
    if (!flags[y]) return;
    const float px = pos_skip[y*3+0], py = pos_skip[y*3+1], pz = pos_skip[y*3+2];
    const int by = batch_skip[y];
    float b0 = INFINITY, b1 = INFINITY, b2 = INFINITY;
    int i0 = 0, i1 = 0, i2 = 0;
    auto ins = [&](float d, int gj) {
        if (d < b2) {
            if (d < b1) {
                b2 = b1; i2 = i1;
                if (d < b0) { b1 = b0; i1 = i0; b0 = d; i0 = gj; }
                else        { b1 = d;  i1 = gj; }
            } else { b2 = d; i2 = gj; }
        }
    };
    for (int j = s; j < NC; j += 64) {
        const float dx = px - pos[j*3+0];
        const float dy = py - pos[j*3+1];
        const float dz = pz - pos[j*3+2];
        float d = dx*dx + dy*dy + dz*dz;
        if (batch[j] != by) d = INFINITY;
        ins(d, j);
    }
    #pragma unroll
    for (int mask = 1; mask <= 32; mask <<= 1) {
        float c0 = __shfl_xor(b0, mask), c1 = __shfl_xor(b1, mask), c2 = __shfl_xor(b2, mask);
        int   j0 = __shfl_xor(i0, mask), j1 = __shfl_xor(i1, mask), j2 = __shfl_xor(i2, mask);
        ins(c0, j0); ins(c1, j1); ins(c2, j2);
    }
    if (s == 0) {
        idx3[y*3+0] = i0; idx3[y*3+1] = i1; idx3[y*3+2] = i2;
        w3[y*3+0] = 1.0f / fmaxf(b0, 1e-16f);
        w3[y*3+1] = 1.0f / fmaxf(b1, 1e-16f);
        w3[y*3+2] = 1.0f / fmaxf(b2, 1e-16f);
    }
}

// ---------------- interpolate + concat -> X0 fp32 + Xb0 bf16 ----------------
__global__ __launch_bounds__(64) void interp_kernel(
    const float* __restrict__ x, const float* __restrict__ x_skip,
    const int* __restrict__ idx3, const float* __restrict__ w3,
    float* __restrict__ X0, __hip_bfloat16* __restrict__ Xb0)
{
    const int n = blockIdx.x, c = threadIdx.x;
    const int j0 = idx3[n*3+0], j1 = idx3[n*3+1], j2 = idx3[n*3+2];
    const float w0 = w3[n*3+0], w1 = w3[n*3+1], w2 = w3[n*3+2];
    const float inv = 1.0f / (w0 + w1 + w2);
    const float h = (w0 * x[j0*64+c] + w1 * x[j1*64+c] + w2 * x[j2*64+c]) * inv;
    const float xs = x_skip[n*64+c];
    X0[(size_t)n*128 + c]      = h;
    X0[(size_t)n*128 + 64 + c] = xs;
    Xb0[(size_t)n*128 + c]      = __float2bfloat16(h);
    Xb0[(size_t)n*128 + 64 + c] = __float2bfloat16(xs);
}

// ---------------- spline basis per edge + dst histogram ----------------
__global__ __launch_bounds__(256) void basis_kernel(
    const int* __restrict__ ei, const float* __restrict__ pos_skip,
    float* __restrict__ basis, uint2* __restrict__ wi8, int* __restrict__ cntD)
{
    const int e = blockIdx.x * 256 + threadIdx.x;
    const int src = ei[e], dst = ei[NE + e];
    float fr[3]; int lo[3];
    #pragma unroll
    for (int d = 0; d < 3; ++d) {
        float p = (pos_skip[dst*3+d] - pos_skip[src*3+d]) * 4.0f + 0.5f;
        p = fminf(fmaxf(p, 0.0f), 1.0f);
        float v = p * 4.0f;
        float l = fminf(floorf(v), 3.0f);
        fr[d] = v - l;
        lo[d] = (int)l;
    }
    unsigned int wlo = 0, whi = 0;
    #pragma unroll
    for (int s = 0; s < 8; ++s) {
        const int bit0 = s & 1, bit1 = (s >> 1) & 1, bit2 = (s >> 2) & 1;
        float b = (bit0 ? fr[0] : 1.0f - fr[0])
                * (bit1 ? fr[1] : 1.0f - fr[1])
                * (bit2 ? fr[2] : 1.0f - fr[2]);
        int w = (lo[0] + bit0) + 5 * (lo[1] + bit1) + 25 * (lo[2] + bit2);
        basis[(size_t)e*8 + s] = b;
        if (s < 4) wlo |= ((unsigned)w) << (8*s);
        else       whi |= ((unsigned)w) << (8*(s-4));
    }
    wi8[e] = make_uint2(wlo, whi);
    atomicAdd(&cntD[dst], 1);
}

// ---------------- exclusive scan over NF counts, single pass (16/thread) ----------------
__global__ __launch_bounds__(1024) void scan1_kernel(
    const int* __restrict__ cnt, int* __restrict__ offs, int* __restrict__ cursor)
{
    __shared__ int s[1024];
    const int tid = threadIdx.x;
    const int base = tid * 16;
    int v[16];
    *(int4*)&v[0]  = *(const int4*)&cnt[base];
    *(int4*)&v[4]  = *(const int4*)&cnt[base+4];
    *(int4*)&v[8]  = *(const int4*)&cnt[base+8];
    *(int4*)&v[12] = *(const int4*)&cnt[base+12];
    int tsum = 0;
    #pragma unroll
    for (int j = 0; j < 16; ++j) tsum += v[j];
    s[tid] = tsum;
    __syncthreads();
    for (int off = 1; off < 1024; off <<= 1) {
        int t = (tid >= off) ? s[tid - off] : 0;
        __syncthreads();
        s[tid] += t;
        __syncthreads();
    }
    int run = s[tid] - tsum;
    #pragma unroll
    for (int j = 0; j < 16; ++j) { offs[base+j] = run; cursor[base+j] = run; run += v[j]; }
    if (tid == 1023) offs[NF] = run;
}

// ---------------- scatter: dst-sorted edge permutation ----------------
__global__ __launch_bounds__(256) void scatter1_kernel(
    const int* __restrict__ ei, int* __restrict__ cur, int* __restrict__ perm)
{
    const int e = blockIdx.x * 256 + threadIdx.x;
    const int p = atomicAdd(&cur[ei[NE + e]], 1);
    perm[p] = e;
}

// ---------------- W prep, all 3 layers: [125][KIN][64] fp32 -> [125][64][KIN] bf16 ----------------
__global__ __launch_bounds__(256) void wprep_all_kernel(
    const float* __restrict__ W0, const float* __restrict__ W1, const float* __restrict__ W2,
    __hip_bfloat16* __restrict__ Wt0, __hip_bfloat16* __restrict__ Wt1, __hip_bfloat16* __restrict__ Wt2)
{
    const int which = blockIdx.y;
    const float* W = (which == 0) ? W0 : (which == 1 ? W1 : W2);
    __hip_bfloat16* Wt = (which == 0) ? Wt0 : (which == 1 ? Wt1 : Wt2);
    const int KIN = (which == 0) ? 128 : 64;
    __shared__ float s[128*64];
    const int kern = blockIdx.x;
    const float* Wk = W + (size_t)kern * KIN * 64;
    for (int i = threadIdx.x; i < KIN*64; i += 256) s[i] = Wk[i];
    __syncthreads();
    const int nk8 = KIN/8;
    for (int i = threadIdx.x; i < 64*nk8; i += 256) {
        const int o = i / nk8, kb = (i % nk8) * 8;
        union { short8v v; __hip_bfloat16 h[8]; } u;
        #pragma unroll
        for (int j = 0; j < 8; ++j) u.h[j] = __float2bfloat16(s[(kb+j)*64 + o]);
        *(short8v*)&Wt[((size_t)kern*64 + o)*KIN + kb] = u.v;
    }
}

// ---------------- T = Xb @ W, fp8 out, row-pair interleaved layout ----------------
// T addr(n,k,c) = (n>>1)*TPAIR + k*128 + (n&1)*64 + c  -> block writes full 128-B lines.
// 1D grid, XCD swizzle: m0 = (bid&127)<<7 (fast), kern = bid>>7.
template<int KIN>
__global__ __launch_bounds__(256) void gemm_fp8_kernel(
    const __hip_bfloat16* __restrict__ Xb,   // [NF][KIN] bf16
    const __hip_bfloat16* __restrict__ Wt,   // [125][64][KIN]
    unsigned char* __restrict__ T)
{
    constexpr int BKP = KIN + 8;
    __shared__ char AsRaw[34816];            // bf16 A-staging [128][BKP] / fp32 C-tile [128][68]
    __shared__ __hip_bfloat16 Bs[64*BKP];
    __hip_bfloat16* As = (__hip_bfloat16*)AsRaw;
    const int bid  = blockIdx.x;
    const int m0   = (bid & 127) << 7;
    const int kern = bid >> 7;

    for (int i = threadIdx.x; i < 128*(KIN/8); i += 256) {
        const int r = i / (KIN/8), c8 = (i % (KIN/8)) * 8;
        *(short8v*)&As[r*BKP + c8] = *(const short8v*)&Xb[(size_t)(m0 + r)*KIN + c8];
    }
    const __hip_bfloat16* Wk = Wt + (size_t)kern * 64 * KIN;
    for (int i = threadIdx.x; i < 64*(KIN/8); i += 256) {
        const int r = i / (KIN/8), c8 = (i % (KIN/8)) * 8;
        *(short8v*)&Bs[r*BKP + c8] = *(const short8v*)&Wk[(size_t)r*KIN + c8];
    }
    __syncthreads();

    const int wid  = threadIdx.x >> 6;
    const int lane = threadIdx.x & 63;
    const int lr   = lane & 15;
    const int lk   = (lane >> 4) * 8;

    f32x4 acc[2][4] = {};
    #pragma unroll
    for (int ks = 0; ks < KIN/32; ++ks) {
        short8v a0 = *(const short8v*)&As[(wid*32 +      lr)*BKP + ks*32 + lk];
        short8v a1 = *(const short8v*)&As[(wid*32 + 16 + lr)*BKP + ks*32 + lk];
        #pragma unroll
        for (int n = 0; n < 4; ++n) {
            short8v b = *(const short8v*)&Bs[(n*16 + lr)*BKP + ks*32 + lk];
            acc[0][n] = __builtin_amdgcn_mfma_f32_16x16x32_bf16(a0, b, acc[0][n], 0, 0, 0);
            acc[1][n] = __builtin_amdgcn_mfma_f32_16x16x32_bf16(a1, b, acc[1][n], 0, 0, 0);
        }
    }

    // epilogue: fp32 C-tile transpose in LDS
    __syncthreads();
    float* Ct = (float*)AsRaw;
    #pragma unroll
    for (int m = 0; m < 2; ++m) {
        const int rowL = wid*32 + m*16 + (lane >> 4)*4;
        #pragma unroll
        for (int n = 0; n < 4; ++n) {
            const int colL = n*16 + lr;
            #pragma unroll
            for (int i = 0; i < 4; ++i)
                Ct[(rowL + i)*68 + colL] = acc[m][n][i];
        }
    }
    __syncthreads();
    // store: 64 row-pairs x 8 chunks of 16 fp8 bytes; threads 0..7 -> one full 128-B line
    #pragma unroll
    for (int u = threadIdx.x; u < 512; u += 256) {
        const int rp = u >> 3, q = u & 7;
        const int row = rp*2 + (q >> 2), ch = (q & 3) * 16;
        const float* p = &Ct[row*68 + ch];
        const float4 f0 = *(const float4*)p;
        const float4 f1 = *(const float4*)(p + 4);
        const float4 f2 = *(const float4*)(p + 8);
        const float4 f3 = *(const float4*)(p + 12);
        int w0 = __builtin_amdgcn_cvt_pk_fp8_f32(f0.x, f0.y, 0, false);
        w0     = __builtin_amdgcn_cvt_pk_fp8_f32(f0.z, f0.w, w0, true);
        int w1 = __builtin_amdgcn_cvt_pk_fp8_f32(f1.x, f1.y, 0, false);
        w1     = __builtin_amdgcn_cvt_pk_fp8_f32(f1.z, f1.w, w1, true);
        int w2 = __builtin_amdgcn_cvt_pk_fp8_f32(f2.x, f2.y, 0, false);
        w2     = __builtin_amdgcn_cvt_pk_fp8_f32(f2.z, f2.w, w2, true);
        int w3 = __builtin_amdgcn_cvt_pk_fp8_f32(f3.x, f3.y, 0, false);
        w3     = __builtin_amdgcn_cvt_pk_fp8_f32(f3.z, f3.w, w3, true);
        *(int4*)&T[((size_t)((m0 >> 1) + rp))*TPAIR + (size_t)kern*128 + q*16] =
            make_int4(w0, w1, w2, w3);
    }
}

// ---------------- FUSED agg: per-dst fp8 tap gather + mean + root + bias + ELU (+tail) ----------------
template<int KIN>
__global__ __launch_bounds__(64) void agg_fp8_kernel(
    const unsigned char* __restrict__ T, const float* __restrict__ basis,
    const uint2* __restrict__ wi8, const int* __restrict__ permD,
    const int* __restrict__ offsD, const int* __restrict__ cntD,
    const int* __restrict__ esrc,
    const float* __restrict__ X, const float* __restrict__ root,
    const float* __restrict__ bias, float* __restrict__ Xout,
    __hip_bfloat16* __restrict__ Xbout,
    const float* __restrict__ tpos, const int* __restrict__ tbatch)
{
    const int n = blockIdx.x, c = threadIdx.x;
    float a = 0.0f;
    const int beg = offsD[n], num = cntD[n];
    auto deq = [](unsigned char b) {
        __hip_fp8_e4m3 v; v.__x = b;
        return (float)v;
    };
    for (int t = 0; t < num; ++t) {
        const int e = permD[beg + t];
        const int src = esrc[e];
        const uint2 w8 = wi8[e];
        const float4 bl = *(const float4*)(basis + (size_t)e*8);
        const float4 bh = *(const float4*)(basis + (size_t)e*8 + 4);
        const unsigned char* Trow = T + (size_t)(src >> 1)*TPAIR + (src & 1)*64 + c;
        a += bl.x * deq(Trow[((w8.x      ) & 255)*128]);
        a += bl.y * deq(Trow[((w8.x >>  8) & 255)*128]);
        a += bl.z * deq(Trow[((w8.x >> 16) & 255)*128]);
        a += bl.w * deq(Trow[((w8.x >> 24) & 255)*128]);
        a += bh.x * deq(Trow[((w8.y      ) & 255)*128]);
        a += bh.y * deq(Trow[((w8.y >>  8) & 255)*128]);
        a += bh.z * deq(Trow[((w8.y >> 16) & 255)*128]);
        a += bh.w * deq(Trow[((w8.y >> 24) & 255)*128]);
    }
    const float agg = a / fmaxf((float)num, 1.0f);
    const float* xr = X + (size_t)n * KIN;
    float r = 0.0f;
    #pragma unroll 16
    for (int i = 0; i < KIN; ++i) r = fmaf(xr[i], root[i*64 + c], r);
    float o = agg + r + bias[c];
    o = (o > 0.0f) ? o : expm1f(o);
    Xout[(size_t)n*64 + c] = o;
    if (Xbout) Xbout[(size_t)n*64 + c] = __float2bfloat16(o);
    if (tpos) {   // final layer: fold tail passthrough
        if (c < 3) Xout[1048576 + n*3 + c] = tpos[n*3 + c];
        if (c == 3) ((int*)Xout)[1048576 + NF*3 + n] = tbatch[n];
    }
}

extern "C" void kernel_launch(void* const* d_in, const int* in_sizes, int n_in,
                              void* d_out, int out_size, void* d_ws, size_t ws_size,
                              hipStream_t stream)
{
    const float* x          = (const float*)d_in[0];
    const float* pos        = (const float*)d_in[1];
    const int*   batch      = (const int*)d_in[2];
    const float* x_skip     = (const float*)d_in[3];
    const float* pos_skip   = (const float*)d_in[4];
    const int*   batch_skip = (const int*)d_in[5];
    const int*   ei         = (const int*)d_in[6];
    const float* W0    = (const float*)d_in[7];
    const float* root0 = (const float*)d_in[8];
    const float* b0    = (const float*)d_in[9];
    const float* W1    = (const float*)d_in[10];
    const float* root1 = (const float*)d_in[11];
    const float* b1    = (const float*)d_in[12];
    const float* W2    = (const float*)d_in[13];
    const float* root2 = (const float*)d_in[14];
    const float* b2    = (const float*)d_in[15];

    char* wp = (char*)d_ws;
    auto carve = [&](size_t bytes) {
        char* p = wp;
        wp += (bytes + 255) & ~(size_t)255;
        return p;
    };
    float* X0    = (float*)carve((size_t)NF * 128 * 4);
    float* X1    = (float*)carve((size_t)NF * 64 * 4);
    float* X2    = (float*)carve((size_t)NF * 64 * 4);
    __hip_bfloat16* Xb0 = (__hip_bfloat16*)carve((size_t)NF * 128 * 2);
    __hip_bfloat16* Xb1 = (__hip_bfloat16*)carve((size_t)NF * 64 * 2);
    __hip_bfloat16* Xb2 = (__hip_bfloat16*)carve((size_t)NF * 64 * 2);
    __hip_bfloat16* Wt0 = (__hip_bfloat16*)carve((size_t)125 * 128 * 64 * 2);
    __hip_bfloat16* Wt1 = (__hip_bfloat16*)carve((size_t)125 * 64 * 64 * 2);
    __hip_bfloat16* Wt2 = (__hip_bfloat16*)carve((size_t)125 * 64 * 64 * 2);
    float* basis = (float*)carve((size_t)NE * 8 * 4);
    uint2* wi8   = (uint2*)carve((size_t)NE * 8);
    int*   idx3  = (int*)carve((size_t)NF * 3 * 4);
    float* w3    = (float*)carve((size_t)NF * 3 * 4);
    int* zeroBase = (int*)carve((size_t)(NCELL + 2*NF) * 4);
    int* cellCnt  = zeroBase;
    int* cntD     = zeroBase + NCELL;
    int* flags    = zeroBase + NCELL + NF;
    int*   cellOffs   = (int*)carve((size_t)(NCELL+1) * 4);
    int*   cellCursor = (int*)carve((size_t)NCELL * 4);
    int*   cellId  = (int*)carve((size_t)NC * 4);
    int*   binPts  = (int*)carve((size_t)NC * 4);
    float4* binPB  = (float4*)carve((size_t)NC * 16);
    int*   offsD   = (int*)carve((size_t)(NF+1) * 4);
    int*   curD    = (int*)carve((size_t)NF * 4);
    int*   permD   = (int*)carve((size_t)NE * 4);
    unsigned char* T = (unsigned char*)carve((size_t)(NF/2) * TPAIR);   // 131 MB fp8

    hipMemsetAsync(zeroBase, 0, (size_t)(NCELL + 2*NF) * 4, stream);
    // KNN via uniform grid (wave-per-query, exact + fallback)
    bin_hist_kernel<<<NC/256, 256, 0, stream>>>(pos, cellCnt, cellId);
    bin_scan_kernel<<<1, 512, 0, stream>>>(cellCnt, cellOffs, cellCursor);
    bin_scatter_kernel<<<NC/256, 256, 0, stream>>>(pos, batch, cellId, cellCursor, binPts, binPB);
    knn_wave_kernel<<<NF/4, 256, 0, stream>>>(binPB, binPts, cellOffs,
                                              pos_skip, batch_skip, idx3, w3, flags);
    knn_fallback_kernel<<<NF/4, 256, 0, stream>>>(pos, batch, pos_skip, batch_skip, flags, idx3, w3);
    interp_kernel<<<NF, 64, 0, stream>>>(x, x_skip, idx3, w3, X0, Xb0);
    // edge prep
    basis_kernel<<<NE/256, 256, 0, stream>>>(ei, pos_skip, basis, wi8, cntD);
    scan1_kernel<<<1, 1024, 0, stream>>>(cntD, offsD, curD);
    scatter1_kernel<<<NE/256, 256, 0, stream>>>(ei, curD, permD);
    wprep_all_kernel<<<dim3(125, 3), 256, 0, stream>>>(W0, W1, W2, Wt0, Wt1, Wt2);

    // layer 0 (KIN=128)
    gemm_fp8_kernel<128><<<125*128, 256, 0, stream>>>(Xb0, Wt0, T);
    agg_fp8_kernel<128><<<NF, 64, 0, stream>>>(T, basis, wi8, permD, offsD, cntD, ei,
                                               X0, root0, b0, X1, Xb1, nullptr, nullptr);
    // layer 1 (KIN=64)
    gemm_fp8_kernel<64><<<125*128, 256, 0, stream>>>(Xb1, Wt1, T);
    agg_fp8_kernel<64><<<NF, 64, 0, stream>>>(T, basis, wi8, permD, offsD, cntD, ei,
                                              X1, root1, b1, X2, Xb2, nullptr, nullptr);
    // layer 2 (KIN=64) -> d_out (+tail)
    gemm_fp8_kernel<64><<<125*128, 256, 0, stream>>>(Xb2, Wt2, T);
    agg_fp8_kernel<64><<<NF, 64, 0, stream>>>(T, basis, wi8, permD, offsD, cntD, ei,
                                              X2, root2, b2, (float*)d_out, (__hip_bfloat16*)nullptr,
                                              pos_skip, batch_skip);
}

// Round 18
// 472.235 us; speedup vs baseline: 1.0716x; 1.0716x over previous
//
#include <hip/hip_runtime.h>
#include <hip/hip_bf16.h>
#include <hip/hip_fp8.h>

#define NC 8192
#define NF 16384
#define NE 262144
#define TROW 8000   // 125*64 fp8 bytes per src row
#define GB 8
#define NCELL 512
#define CELLH 0.125f

typedef __attribute__((ext_vector_type(8))) short short8v;  // 8 bf16
typedef __attribute__((ext_vector_type(4))) float f32x4;

// ---------------- binning: histogram over coarse points ----------------
__global__ __launch_bounds__(256) void bin_hist_kernel(
    const float* __restrict__ pos, int* __restrict__ cellCnt, int* __restrict__ cellId)
{
    const int i = blockIdx.x * 256 + threadIdx.x;
    const int cx = min((int)(pos[i*3+0] * GB), GB-1);
    const int cy = min((int)(pos[i*3+1] * GB), GB-1);
    const int cz = min((int)(pos[i*3+2] * GB), GB-1);
    const int cell = (cz*GB + cy)*GB + cx;
    cellId[i] = cell;
    atomicAdd(&cellCnt[cell], 1);
}

// ---------------- binning: scan 512 cells (writes sentinel) ----------------
__global__ __launch_bounds__(512) void bin_scan_kernel(
    const int* __restrict__ cellCnt, int* __restrict__ cellOffs, int* __restrict__ cellCursor)
{
    __shared__ int s[512];
    const int tid = threadIdx.x;
    const int v = cellCnt[tid];
    s[tid] = v;
    __syncthreads();
    for (int off = 1; off < 512; off <<= 1) {
        int t = (tid >= off) ? s[tid - off] : 0;
        __syncthreads();
        s[tid] += t;
        __syncthreads();
    }
    cellOffs[tid] = s[tid] - v;
    cellCursor[tid] = s[tid] - v;
    if (tid == 511) cellOffs[512] = s[511];
}

// ---------------- binning: scatter points -> packed float4 (xyz + batch bits) ----------------
__global__ __launch_bounds__(256) void bin_scatter_kernel(
    const float* __restrict__ pos, const int* __restrict__ batch,
    const int* __restrict__ cellId, int* __restrict__ cellCursor,
    int* __restrict__ binPts, float4* __restrict__ binPB)
{
    const int i = blockIdx.x * 256 + threadIdx.x;
    const int cell = cellId[i];
    const int p = atomicAdd(&cellCursor[cell], 1);
    binPts[p] = i;
    float4 q;
    q.x = pos[i*3+0]; q.y = pos[i*3+1]; q.z = pos[i*3+2];
    q.w = __int_as_float(batch[i]);
    binPB[p] = q;
}

// ---------------- KNN: one wave per query, 9 contiguous ranges, no LDS ----------------
__global__ __launch_bounds__(256) void knn_wave_kernel(
    const float4* __restrict__ binPB, const int* __restrict__ binPts,
    const int* __restrict__ cellOffs,
    const float* __restrict__ pos_skip, const int* __restrict__ batch_skip,
    int* __restrict__ idx3, float* __restrict__ w3, int* __restrict__ flags)
{
    const int lane = threadIdx.x & 63;
    const int y = blockIdx.x * 4 + (threadIdx.x >> 6);
    const float px = pos_skip[y*3+0], py = pos_skip[y*3+1], pz = pos_skip[y*3+2];
    const int by = batch_skip[y];
    const int cx = min((int)(px * GB), GB-1);
    const int cy = min((int)(py * GB), GB-1);
    const int cz = min((int)(pz * GB), GB-1);
    const int xlo = max(cx-1,0), xhi = min(cx+1,GB-1);
    const int ylo = max(cy-1,0), yhi = min(cy+1,GB-1);
    const int zlo = max(cz-1,0), zhi = min(cz+1,GB-1);

    float b0 = INFINITY, b1 = INFINITY, b2 = INFINITY;
    int i0 = 0, i1 = 0, i2 = 0;
    auto ins = [&](float d, int gj) {
        if (d < b2) {
            if (d < b1) {
                b2 = b1; i2 = i1;
                if (d < b0) { b1 = b0; i1 = i0; b0 = d; i0 = gj; }
                else        { b1 = d;  i1 = gj; }
            } else { b2 = d; i2 = gj; }
        }
    };

    for (int zz = zlo; zz <= zhi; ++zz)
    for (int yy = ylo; yy <= yhi; ++yy) {
        const int rowb = (zz*GB + yy)*GB;
        const int b = cellOffs[rowb + xlo];
        const int e = cellOffs[rowb + xhi + 1];
        for (int p = b + lane; p < e; p += 64) {
            const float4 q = binPB[p];
            const float dx = px - q.x, dy = py - q.y, dz = pz - q.z;
            float d = dx*dx + dy*dy + dz*dz;
            if (__float_as_int(q.w) != by) d = INFINITY;
            ins(d, binPts[p]);
        }
    }
    #pragma unroll
    for (int mask = 1; mask <= 32; mask <<= 1) {
        float c0 = __shfl_xor(b0, mask), c1 = __shfl_xor(b1, mask), c2 = __shfl_xor(b2, mask);
        int   j0 = __shfl_xor(i0, mask), j1 = __shfl_xor(i1, mask), j2 = __shfl_xor(i2, mask);
        ins(c0, j0); ins(c1, j1); ins(c2, j2);
    }
    if (lane == 0) {
        float rd = 1e30f;
        if (cx > 0)    rd = fminf(rd, px - (cx-1)*CELLH);
        if (cx < GB-1) rd = fminf(rd, (cx+2)*CELLH - px);
        if (cy > 0)    rd = fminf(rd, py - (cy-1)*CELLH);
        if (cy < GB-1) rd = fminf(rd, (cy+2)*CELLH - py);
        if (cz > 0)    rd = fminf(rd, pz - (cz-1)*CELLH);
        if (cz < GB-1) rd = fminf(rd, (cz+2)*CELLH - pz);
        if (!(b2 <= rd*rd)) flags[y] = 1;
        idx3[y*3+0] = i0; idx3[y*3+1] = i1; idx3[y*3+2] = i2;
        w3[y*3+0] = 1.0f / fmaxf(b0, 1e-16f);
        w3[y*3+1] = 1.0f / fmaxf(b1, 1e-16f);
        w3[y*3+2] = 1.0f / fmaxf(b2, 1e-16f);
    }
}

// ---------------- KNN fallback: exact brute force for flagged queries ----------------
__global__ __launch_bounds__(256) void knn_fallback_kernel(
    const float* __restrict__ pos, const int* __restrict__ batch,
    const float* __restrict__ pos_skip, const int* __restrict__ batch_skip,
    const int* __restrict__ flags, int* __restrict__ idx3, float* __restrict__ w3)
{
    const int s = threadIdx.x & 63;
    const int y = blockIdx.x * 4 + (threadIdx.x >> 6);
    if (!flags[y]) return;
    const float px = pos_skip[y*3+0], py = pos_skip[y*3+1], pz = pos_skip[y*3+2];
    const int by = batch_skip[y];
    float b0 = INFINITY, b1 = INFINITY, b2 = INFINITY;
    int i0 = 0, i1 = 0, i2 = 0;
    auto ins = [&](float d, int gj) {
        if (d < b2) {
            if (d < b1) {
                b2 = b1; i2 = i1;
                if (d < b0) { b1 = b0; i1 = i0; b0 = d; i0 = gj; }
                else        { b1 = d;  i1 = gj; }
            } else { b2 = d; i2 = gj; }
        }
    };
    for (int j = s; j < NC; j += 64) {
        const float dx = px - pos[j*3+0];
        const float dy = py - pos[j*3+1];
        const float dz = pz - pos[j*3+2];
        float d = dx*dx + dy*dy + dz*dz;
        if (batch[j] != by) d = INFINITY;
        ins(d, j);
    }
    #pragma unroll
    for (int mask = 1; mask <= 32; mask <<= 1) {
        float c0 = __shfl_xor(b0, mask), c1 = __shfl_xor(b1, mask), c2 = __shfl_xor(b2, mask);
        int   j0 = __shfl_xor(i0, mask), j1 = __shfl_xor(i1, mask), j2 = __shfl_xor(i2, mask);
        ins(c0, j0); ins(c1, j1); ins(c2, j2);
    }
    if (s == 0) {
        idx3[y*3+0] = i0; idx3[y*3+1] = i1; idx3[y*3+2] = i2;
        w3[y*3+0] = 1.0f / fmaxf(b0, 1e-16f);
        w3[y*3+1] = 1.0f / fmaxf(b1, 1e-16f);
        w3[y*3+2] = 1.0f / fmaxf(b2, 1e-16f);
    }
}

// ---------------- interpolate + concat -> X0 fp32 + Xb0 bf16 ----------------
__global__ __launch_bounds__(64) void interp_kernel(
    const float* __restrict__ x, const float* __restrict__ x_skip,
    const int* __restrict__ idx3, const float* __restrict__ w3,
    float* __restrict__ X0, __hip_bfloat16* __restrict__ Xb0)
{
    const int n = blockIdx.x, c = threadIdx.x;
    const int j0 = idx3[n*3+0], j1 = idx3[n*3+1], j2 = idx3[n*3+2];
    const float w0 = w3[n*3+0], w1 = w3[n*3+1], w2 = w3[n*3+2];
    const float inv = 1.0f / (w0 + w1 + w2);
    const float h = (w0 * x[j0*64+c] + w1 * x[j1*64+c] + w2 * x[j2*64+c]) * inv;
    const float xs = x_skip[n*64+c];
    X0[(size_t)n*128 + c]      = h;
    X0[(size_t)n*128 + 64 + c] = xs;
    Xb0[(size_t)n*128 + c]      = __float2bfloat16(h);
    Xb0[(size_t)n*128 + 64 + c] = __float2bfloat16(xs);
}

// ---------------- spline basis per edge + dst histogram ----------------
__global__ __launch_bounds__(256) void basis_kernel(
    const int* __restrict__ ei, const float* __restrict__ pos_skip,
    float* __restrict__ basis, uint2* __restrict__ wi8, int* __restrict__ cntD)
{
    const int e = blockIdx.x * 256 + threadIdx.x;
    const int src = ei[e], dst = ei[NE + e];
    float fr[3]; int lo[3];
    #pragma unroll
    for (int d = 0; d < 3; ++d) {
        float p = (pos_skip[dst*3+d] - pos_skip[src*3+d]) * 4.0f + 0.5f;
        p = fminf(fmaxf(p, 0.0f), 1.0f);
        float v = p * 4.0f;
        float l = fminf(floorf(v), 3.0f);
        fr[d] = v - l;
        lo[d] = (int)l;
    }
    unsigned int wlo = 0, whi = 0;
    #pragma unroll
    for (int s = 0; s < 8; ++s) {
        const int bit0 = s & 1, bit1 = (s >> 1) & 1, bit2 = (s >> 2) & 1;
        float b = (bit0 ? fr[0] : 1.0f - fr[0])
                * (bit1 ? fr[1] : 1.0f - fr[1])
                * (bit2 ? fr[2] : 1.0f - fr[2]);
        int w = (lo[0] + bit0) + 5 * (lo[1] + bit1) + 25 * (lo[2] + bit2);
        basis[(size_t)e*8 + s] = b;
        if (s < 4) wlo |= ((unsigned)w) << (8*s);
        else       whi |= ((unsigned)w) << (8*(s-4));
    }
    wi8[e] = make_uint2(wlo, whi);
    atomicAdd(&cntD[dst], 1);
}

// ---------------- exclusive scan over NF counts, single pass (16/thread) ----------------
__global__ __launch_bounds__(1024) void scan1_kernel(
    const int* __restrict__ cnt, int* __restrict__ offs, int* __restrict__ cursor)
{
    __shared__ int s[1024];
    const int tid = threadIdx.x;
    const int base = tid * 16;
    int v[16];
    *(int4*)&v[0]  = *(const int4*)&cnt[base];
    *(int4*)&v[4]  = *(const int4*)&cnt[base+4];
    *(int4*)&v[8]  = *(const int4*)&cnt[base+8];
    *(int4*)&v[12] = *(const int4*)&cnt[base+12];
    int tsum = 0;
    #pragma unroll
    for (int j = 0; j < 16; ++j) tsum += v[j];
    s[tid] = tsum;
    __syncthreads();
    for (int off = 1; off < 1024; off <<= 1) {
        int t = (tid >= off) ? s[tid - off] : 0;
        __syncthreads();
        s[tid] += t;
        __syncthreads();
    }
    int run = s[tid] - tsum;
    #pragma unroll
    for (int j = 0; j < 16; ++j) { offs[base+j] = run; cursor[base+j] = run; run += v[j]; }
    if (tid == 1023) offs[NF] = run;
}

// ---------------- scatter: dst-sorted edge permutation ----------------
__global__ __launch_bounds__(256) void scatter1_kernel(
    const int* __restrict__ ei, int* __restrict__ cur, int* __restrict__ perm)
{
    const int e = blockIdx.x * 256 + threadIdx.x;
    const int p = atomicAdd(&cur[ei[NE + e]], 1);
    perm[p] = e;
}

// ---------------- W prep, all 3 layers: [125][KIN][64] fp32 -> [125][64][KIN] bf16 ----------------
__global__ __launch_bounds__(256) void wprep_all_kernel(
    const float* __restrict__ W0, const float* __restrict__ W1, const float* __restrict__ W2,
    __hip_bfloat16* __restrict__ Wt0, __hip_bfloat16* __restrict__ Wt1, __hip_bfloat16* __restrict__ Wt2)
{
    const int which = blockIdx.y;
    const float* W = (which == 0) ? W0 : (which == 1 ? W1 : W2);
    __hip_bfloat16* Wt = (which == 0) ? Wt0 : (which == 1 ? Wt1 : Wt2);
    const int KIN = (which == 0) ? 128 : 64;
    __shared__ float s[128*64];
    const int kern = blockIdx.x;
    const float* Wk = W + (size_t)kern * KIN * 64;
    for (int i = threadIdx.x; i < KIN*64; i += 256) s[i] = Wk[i];
    __syncthreads();
    const int nk8 = KIN/8;
    for (int i = threadIdx.x; i < 64*nk8; i += 256) {
        const int o = i / nk8, kb = (i % nk8) * 8;
        union { short8v v; __hip_bfloat16 h[8]; } u;
        #pragma unroll
        for (int j = 0; j < 8; ++j) u.h[j] = __float2bfloat16(s[(kb+j)*64 + o]);
        *(short8v*)&Wt[((size_t)kern*64 + o)*KIN + kb] = u.v;
    }
}

// ---------------- T = Xb @ W, fp8 out; 5 kerns/block, A-tile reused, union B/C LDS ----------------
// grid: 25 kern-groups x 128 m-tiles (m0 fast -> XCD-local A tiles).
template<int KIN>
__global__ __launch_bounds__(256) void gemm_fp8_kernel(
    const __hip_bfloat16* __restrict__ Xb,   // [NF][KIN] bf16
    const __hip_bfloat16* __restrict__ Wt,   // [125][64][KIN]
    unsigned char* __restrict__ T)           // [NF][TROW] fp8
{
    constexpr int BKP = KIN + 8;
    __shared__ __hip_bfloat16 As[128*BKP];   // persistent A tile
    __shared__ char URaw[34816];             // union: B bf16 [64][BKP] / C fp32 [128][68]
    __hip_bfloat16* Bs = (__hip_bfloat16*)URaw;
    float* Ct = (float*)URaw;
    const int bid = blockIdx.x;
    const int m0  = (bid & 127) << 7;        // fast index -> per-XCD A-tile residency
    const int kg  = bid >> 7;                // 0..24

    for (int i = threadIdx.x; i < 128*(KIN/8); i += 256) {
        const int r = i / (KIN/8), c8 = (i % (KIN/8)) * 8;
        *(short8v*)&As[r*BKP + c8] = *(const short8v*)&Xb[(size_t)(m0 + r)*KIN + c8];
    }

    const int wid  = threadIdx.x >> 6;
    const int lane = threadIdx.x & 63;
    const int lr   = lane & 15;
    const int lk   = (lane >> 4) * 8;

    for (int j = 0; j < 5; ++j) {
        const int kern = kg*5 + j;
        __syncthreads();                     // prev store reads of U done (and A ready, j=0)
        const __hip_bfloat16* Wk = Wt + (size_t)kern * 64 * KIN;
        for (int i = threadIdx.x; i < 64*(KIN/8); i += 256) {
            const int r = i / (KIN/8), c8 = (i % (KIN/8)) * 8;
            *(short8v*)&Bs[r*BKP + c8] = *(const short8v*)&Wk[(size_t)r*KIN + c8];
        }
        __syncthreads();

        f32x4 acc[2][4] = {};
        #pragma unroll
        for (int ks = 0; ks < KIN/32; ++ks) {
            short8v a0 = *(const short8v*)&As[(wid*32 +      lr)*BKP + ks*32 + lk];
            short8v a1 = *(const short8v*)&As[(wid*32 + 16 + lr)*BKP + ks*32 + lk];
            #pragma unroll
            for (int n = 0; n < 4; ++n) {
                short8v b = *(const short8v*)&Bs[(n*16 + lr)*BKP + ks*32 + lk];
                acc[0][n] = __builtin_amdgcn_mfma_f32_16x16x32_bf16(a0, b, acc[0][n], 0, 0, 0);
                acc[1][n] = __builtin_amdgcn_mfma_f32_16x16x32_bf16(a1, b, acc[1][n], 0, 0, 0);
            }
        }
        __syncthreads();                     // all B reads done before C overwrites U

        #pragma unroll
        for (int m = 0; m < 2; ++m) {
            const int rowL = wid*32 + m*16 + (lane >> 4)*4;
            #pragma unroll
            for (int n = 0; n < 4; ++n) {
                const int colL = n*16 + lr;
                #pragma unroll
                for (int i = 0; i < 4; ++i)
                    Ct[(rowL + i)*68 + colL] = acc[m][n][i];
            }
        }
        __syncthreads();

        #pragma unroll
        for (int u = threadIdx.x; u < 512; u += 256) {
            const int row = u >> 2, ch = (u & 3) * 16;
            const float* p = &Ct[row*68 + ch];
            const float4 f0 = *(const float4*)p;
            const float4 f1 = *(const float4*)(p + 4);
            const float4 f2 = *(const float4*)(p + 8);
            const float4 f3 = *(const float4*)(p + 12);
            int w0 = __builtin_amdgcn_cvt_pk_fp8_f32(f0.x, f0.y, 0, false);
            w0     = __builtin_amdgcn_cvt_pk_fp8_f32(f0.z, f0.w, w0, true);
            int w1 = __builtin_amdgcn_cvt_pk_fp8_f32(f1.x, f1.y, 0, false);
            w1     = __builtin_amdgcn_cvt_pk_fp8_f32(f1.z, f1.w, w1, true);
            int w2 = __builtin_amdgcn_cvt_pk_fp8_f32(f2.x, f2.y, 0, false);
            w2     = __builtin_amdgcn_cvt_pk_fp8_f32(f2.z, f2.w, w2, true);
            int w3 = __builtin_amdgcn_cvt_pk_fp8_f32(f3.x, f3.y, 0, false);
            w3     = __builtin_amdgcn_cvt_pk_fp8_f32(f3.z, f3.w, w3, true);
            *(int4*)&T[(size_t)(m0 + row)*TROW + kern*64 + ch] = make_int4(w0, w1, w2, w3);
        }
    }
}

// ---------------- FUSED agg: per-dst fp8 tap gather + mean + root + bias + ELU (+tail) ----------------
template<int KIN>
__global__ __launch_bounds__(64) void agg_fp8_kernel(
    const unsigned char* __restrict__ T, const float* __restrict__ basis,
    const uint2* __restrict__ wi8, const int* __restrict__ permD,
    const int* __restrict__ offsD, const int* __restrict__ cntD,
    const int* __restrict__ esrc,
    const float* __restrict__ X, const float* __restrict__ root,
    const float* __restrict__ bias, float* __restrict__ Xout,
    __hip_bfloat16* __restrict__ Xbout,
    const float* __restrict__ tpos, const int* __restrict__ tbatch)
{
    const int n = blockIdx.x, c = threadIdx.x;
    float a = 0.0f;
    const int beg = offsD[n], num = cntD[n];
    auto deq = [](unsigned char b) {
        __hip_fp8_e4m3 v; v.__x = b;
        return (float)v;
    };
    for (int t = 0; t < num; ++t) {
        const int e = permD[beg + t];
        const uint2 w8 = wi8[e];
        const float4 bl = *(const float4*)(basis + (size_t)e*8);
        const float4 bh = *(const float4*)(basis + (size_t)e*8 + 4);
        const unsigned char* Trow = T + (size_t)esrc[e] * TROW + c;
        a += bl.x * deq(Trow[((w8.x      ) & 255)*64]);
        a += bl.y * deq(Trow[((w8.x >>  8) & 255)*64]);
        a += bl.z * deq(Trow[((w8.x >> 16) & 255)*64]);
        a += bl.w * deq(Trow[((w8.x >> 24) & 255)*64]);
        a += bh.x * deq(Trow[((w8.y      ) & 255)*64]);
        a += bh.y * deq(Trow[((w8.y >>  8) & 255)*64]);
        a += bh.z * deq(Trow[((w8.y >> 16) & 255)*64]);
        a += bh.w * deq(Trow[((w8.y >> 24) & 255)*64]);
    }
    const float agg = a / fmaxf((float)num, 1.0f);
    const float* xr = X + (size_t)n * KIN;
    float r = 0.0f;
    #pragma unroll 16
    for (int i = 0; i < KIN; ++i) r = fmaf(xr[i], root[i*64 + c], r);
    float o = agg + r + bias[c];
    o = (o > 0.0f) ? o : expm1f(o);
    Xout[(size_t)n*64 + c] = o;
    if (Xbout) Xbout[(size_t)n*64 + c] = __float2bfloat16(o);
    if (tpos) {   // final layer: fold tail passthrough
        if (c < 3) Xout[1048576 + n*3 + c] = tpos[n*3 + c];
        if (c == 3) ((int*)Xout)[1048576 + NF*3 + n] = tbatch[n];
    }
}

extern "C" void kernel_launch(void* const* d_in, const int* in_sizes, int n_in,
                              void* d_out, int out_size, void* d_ws, size_t ws_size,
                              hipStream_t stream)
{
    const float* x          = (const float*)d_in[0];
    const float* pos        = (const float*)d_in[1];
    const int*   batch      = (const int*)d_in[2];
    const float* x_skip     = (const float*)d_in[3];
    const float* pos_skip   = (const float*)d_in[4];
    const int*   batch_skip = (const int*)d_in[5];
    const int*   ei         = (const int*)d_in[6];
    const float* W0    = (const float*)d_in[7];
    const float* root0 = (const float*)d_in[8];
    const float* b0    = (const float*)d_in[9];
    const float* W1    = (const float*)d_in[10];
    const float* root1 = (const float*)d_in[11];
    const float* b1    = (const float*)d_in[12];
    const float* W2    = (const float*)d_in[13];
    const float* root2 = (const float*)d_in[14];
    const float* b2    = (const float*)d_in[15];

    char* wp = (char*)d_ws;
    auto carve = [&](size_t bytes) {
        char* p = wp;
        wp += (bytes + 255) & ~(size_t)255;
        return p;
    };
    float* X0    = (float*)carve((size_t)NF * 128 * 4);
    float* X1    = (float*)carve((size_t)NF * 64 * 4);
    float* X2    = (float*)carve((size_t)NF * 64 * 4);
    __hip_bfloat16* Xb0 = (__hip_bfloat16*)carve((size_t)NF * 128 * 2);
    __hip_bfloat16* Xb1 = (__hip_bfloat16*)carve((size_t)NF * 64 * 2);
    __hip_bfloat16* Xb2 = (__hip_bfloat16*)carve((size_t)NF * 64 * 2);
    __hip_bfloat16* Wt0 = (__hip_bfloat16*)carve((size_t)125 * 128 * 64 * 2);
    __hip_bfloat16* Wt1 = (__hip_bfloat16*)carve((size_t)125 * 64 * 64 * 2);
    __hip_bfloat16* Wt2 = (__hip_bfloat16*)carve((size_t)125 * 64 * 64 * 2);
    float* basis = (float*)carve((size_t)NE * 8 * 4);
    uint2* wi8   = (uint2*)carve((size_t)NE * 8);
    int*   idx3  = (int*)carve((size_t)NF * 3 * 4);
    float* w3    = (float*)carve((size_t)NF * 3 * 4);
    int* zeroBase = (int*)carve((size_t)(NCELL + 2*NF) * 4);
    int* cellCnt  = zeroBase;
    int* cntD     = zeroBase + NCELL;
    int* flags    = zeroBase + NCELL + NF;
    int*   cellOffs   = (int*)carve((size_t)(NCELL+1) * 4);
    int*   cellCursor = (int*)carve((size_t)NCELL * 4);
    int*   cellId  = (int*)carve((size_t)NC * 4);
    int*   binPts  = (int*)carve((size_t)NC * 4);
    float4* binPB  = (float4*)carve((size_t)NC * 16);
    int*   offsD   = (int*)carve((size_t)(NF+1) * 4);
    int*   curD    = (int*)carve((size_t)NF * 4);
    int*   permD   = (int*)carve((size_t)NE * 4);
    unsigned char* T = (unsigned char*)carve((size_t)NF * TROW);   // 131 MB fp8

    hipMemsetAsync(zeroBase, 0, (size_t)(NCELL + 2*NF) * 4, stream);
    // KNN via uniform grid (wave-per-query, exact + fallback)
    bin_hist_kernel<<<NC/256, 256, 0, stream>>>(pos, cellCnt, cellId);
    bin_scan_kernel<<<1, 512, 0, stream>>>(cellCnt, cellOffs, cellCursor);
    bin_scatter_kernel<<<NC/256, 256, 0, stream>>>(pos, batch, cellId, cellCursor, binPts, binPB);
    knn_wave_kernel<<<NF/4, 256, 0, stream>>>(binPB, binPts, cellOffs,
                                              pos_skip, batch_skip, idx3, w3, flags);
    knn_fallback_kernel<<<NF/4, 256, 0, stream>>>(pos, batch, pos_skip, batch_skip, flags, idx3, w3);
    interp_kernel<<<NF, 64, 0, stream>>>(x, x_skip, idx3, w3, X0, Xb0);
    // edge prep
    basis_kernel<<<NE/256, 256, 0, stream>>>(ei, pos_skip, basis, wi8, cntD);
    scan1_kernel<<<1, 1024, 0, stream>>>(cntD, offsD, curD);
    scatter1_kernel<<<NE/256, 256, 0, stream>>>(ei, curD, permD);
    wprep_all_kernel<<<dim3(125, 3), 256, 0, stream>>>(W0, W1, W2, Wt0, Wt1, Wt2);

    // layer 0 (KIN=128)
    gemm_fp8_kernel<128><<<25*128, 256, 0, stream>>>(Xb0, Wt0, T);
    agg_fp8_kernel<128><<<NF, 64, 0, stream>>>(T, basis, wi8, permD, offsD, cntD, ei,
                                               X0, root0, b0, X1, Xb1, nullptr, nullptr);
    // layer 1 (KIN=64)
    gemm_fp8_kernel<64><<<25*128, 256, 0, stream>>>(Xb1, Wt1, T);
    agg_fp8_kernel<64><<<NF, 64, 0, stream>>>(T, basis, wi8, permD, offsD, cntD, ei,
                                              X1, root1, b1, X2, Xb2, nullptr, nullptr);
    // layer 2 (KIN=64) -> d_out (+tail)
    gemm_fp8_kernel<64><<<25*128, 256, 0, stream>>>(Xb2, Wt2, T);
    agg_fp8_kernel<64><<<NF, 64, 0, stream>>>(T, basis, wi8, permD, offsD, cntD, ei,
                                              X2, root2, b2, (float*)d_out, (__hip_bfloat16*)nullptr,
                                              pos_skip, batch_skip);
}

// Round 19
// 467.533 us; speedup vs baseline: 1.0823x; 1.0101x over previous
//
#include <hip/hip_runtime.h>
#include <hip/hip_bf16.h>
#include <hip/hip_fp8.h>

#define NC 8192
#define NF 16384
#define NE 262144
#define TROW 8000   // 125*64 fp8 bytes per src row
#define GB 8
#define NCELL 512
#define CELLH 0.125f

typedef __attribute__((ext_vector_type(8))) short short8v;  // 8 bf16
typedef __attribute__((ext_vector_type(4))) float f32x4;

// ---------------- binning: histogram over coarse points ----------------
__global__ __launch_bounds__(256) void bin_hist_kernel(
    const float* __restrict__ pos, int* __restrict__ cellCnt, int* __restrict__ cellId)
{
    const int i = blockIdx.x * 256 + threadIdx.x;
    const int cx = min((int)(pos[i*3+0] * GB), GB-1);
    const int cy = min((int)(pos[i*3+1] * GB), GB-1);
    const int cz = min((int)(pos[i*3+2] * GB), GB-1);
    const int cell = (cz*GB + cy)*GB + cx;
    cellId[i] = cell;
    atomicAdd(&cellCnt[cell], 1);
}

// ---------------- binning: scan 512 cells (writes sentinel) ----------------
__global__ __launch_bounds__(512) void bin_scan_kernel(
    const int* __restrict__ cellCnt, int* __restrict__ cellOffs, int* __restrict__ cellCursor)
{
    __shared__ int s[512];
    const int tid = threadIdx.x;
    const int v = cellCnt[tid];
    s[tid] = v;
    __syncthreads();
    for (int off = 1; off < 512; off <<= 1) {
        int t = (tid >= off) ? s[tid - off] : 0;
        __syncthreads();
        s[tid] += t;
        __syncthreads();
    }
    cellOffs[tid] = s[tid] - v;
    cellCursor[tid] = s[tid] - v;
    if (tid == 511) cellOffs[512] = s[511];
}

// ---------------- binning: scatter points -> packed float4 (xyz + batch bits) ----------------
__global__ __launch_bounds__(256) void bin_scatter_kernel(
    const float* __restrict__ pos, const int* __restrict__ batch,
    const int* __restrict__ cellId, int* __restrict__ cellCursor,
    int* __restrict__ binPts, float4* __restrict__ binPB)
{
    const int i = blockIdx.x * 256 + threadIdx.x;
    const int cell = cellId[i];
    const int p = atomicAdd(&cellCursor[cell], 1);
    binPts[p] = i;
    float4 q;
    q.x = pos[i*3+0]; q.y = pos[i*3+1]; q.z = pos[i*3+2];
    q.w = __int_as_float(batch[i]);
    binPB[p] = q;
}

// ---------------- KNN: one wave per query, 9 contiguous ranges, no LDS ----------------
__global__ __launch_bounds__(256) void knn_wave_kernel(
    const float4* __restrict__ binPB, const int* __restrict__ binPts,
    const int* __restrict__ cellOffs,
    const float* __restrict__ pos_skip, const int* __restrict__ batch_skip,
    int* __restrict__ idx3, float* __restrict__ w3, int* __restrict__ flags)
{
    const int lane = threadIdx.x & 63;
    const int y = blockIdx.x * 4 + (threadIdx.x >> 6);
    const float px = pos_skip[y*3+0], py = pos_skip[y*3+1], pz = pos_skip[y*3+2];
    const int by = batch_skip[y];
    const int cx = min((int)(px * GB), GB-1);
    const int cy = min((int)(py * GB), GB-1);
    const int cz = min((int)(pz * GB), GB-1);
    const int xlo = max(cx-1,0), xhi = min(cx+1,GB-1);
    const int ylo = max(cy-1,0), yhi = min(cy+1,GB-1);
    const int zlo = max(cz-1,0), zhi = min(cz+1,GB-1);

    float b0 = INFINITY, b1 = INFINITY, b2 = INFINITY;
    int i0 = 0, i1 = 0, i2 = 0;
    auto ins = [&](float d, int gj) {
        if (d < b2) {
            if (d < b1) {
                b2 = b1; i2 = i1;
                if (d < b0) { b1 = b0; i1 = i0; b0 = d; i0 = gj; }
                else        { b1 = d;  i1 = gj; }
            } else { b2 = d; i2 = gj; }
        }
    };

    for (int zz = zlo; zz <= zhi; ++zz)
    for (int yy = ylo; yy <= yhi; ++yy) {
        const int rowb = (zz*GB + yy)*GB;
        const int b = cellOffs[rowb + xlo];
        const int e = cellOffs[rowb + xhi + 1];
        for (int p = b + lane; p < e; p += 64) {
            const float4 q = binPB[p];
            const float dx = px - q.x, dy = py - q.y, dz = pz - q.z;
            float d = dx*dx + dy*dy + dz*dz;
            if (__float_as_int(q.w) != by) d = INFINITY;
            ins(d, binPts[p]);
        }
    }
    #pragma unroll
    for (int mask = 1; mask <= 32; mask <<= 1) {
        float c0 = __shfl_xor(b0, mask), c1 = __shfl_xor(b1, mask), c2 = __shfl_xor(b2, mask);
        int   j0 = __shfl_xor(i0, mask), j1 = __shfl_xor(i1, mask), j2 = __shfl_xor(i2, mask);
        ins(c0, j0); ins(c1, j1); ins(c2, j2);
    }
    if (lane == 0) {
        float rd = 1e30f;
        if (cx > 0)    rd = fminf(rd, px - (cx-1)*CELLH);
        if (cx < GB-1) rd = fminf(rd, (cx+2)*CELLH - px);
        if (cy > 0)    rd = fminf(rd, py - (cy-1)*CELLH);
        if (cy < GB-1) rd = fminf(rd, (cy+2)*CELLH - py);
        if (cz > 0)    rd = fminf(rd, pz - (cz-1)*CELLH);
        if (cz < GB-1) rd = fminf(rd, (cz+2)*CELLH - pz);
        if (!(b2 <= rd*rd)) flags[y] = 1;
        idx3[y*3+0] = i0; idx3[y*3+1] = i1; idx3[y*3+2] = i2;
        w3[y*3+0] = 1.0f / fmaxf(b0, 1e-16f);
        w3[y*3+1] = 1.0f / fmaxf(b1, 1e-16f);
        w3[y*3+2] = 1.0f / fmaxf(b2, 1e-16f);
    }
}

// ---------------- KNN fallback: exact brute force for flagged queries ----------------
__global__ __launch_bounds__(256) void knn_fallback_kernel(
    const float* __restrict__ pos, const int* __restrict__ batch,
    const float* __restrict__ pos_skip, const int* __restrict__ batch_skip,
    const int* __restrict__ flags, int* __restrict__ idx3, float* __restrict__ w3)
{
    const int s = threadIdx.x & 63;
    const int y = blockIdx.x * 4 + (threadIdx.x >> 6);
    if (!flags[y]) return;
    const float px = pos_skip[y*3+0], py = pos_skip[y*3+1], pz = pos_skip[y*3+2];
    const int by = batch_skip[y];
    float b0 = INFINITY, b1 = INFINITY, b2 = INFINITY;
    int i0 = 0, i1 = 0, i2 = 0;
    auto ins = [&](float d, int gj) {
        if (d < b2) {
            if (d < b1) {
                b2 = b1; i2 = i1;
                if (d < b0) { b1 = b0; i1 = i0; b0 = d; i0 = gj; }
                else        { b1 = d;  i1 = gj; }
            } else { b2 = d; i2 = gj; }
        }
    };
    for (int j = s; j < NC; j += 64) {
        const float dx = px - pos[j*3+0];
        const float dy = py - pos[j*3+1];
        const float dz = pz - pos[j*3+2];
        float d = dx*dx + dy*dy + dz*dz;
        if (batch[j] != by) d = INFINITY;
        ins(d, j);
    }
    #pragma unroll
    for (int mask = 1; mask <= 32; mask <<= 1) {
        float c0 = __shfl_xor(b0, mask), c1 = __shfl_xor(b1, mask), c2 = __shfl_xor(b2, mask);
        int   j0 = __shfl_xor(i0, mask), j1 = __shfl_xor(i1, mask), j2 = __shfl_xor(i2, mask);
        ins(c0, j0); ins(c1, j1); ins(c2, j2);
    }
    if (s == 0) {
        idx3[y*3+0] = i0; idx3[y*3+1] = i1; idx3[y*3+2] = i2;
        w3[y*3+0] = 1.0f / fmaxf(b0, 1e-16f);
        w3[y*3+1] = 1.0f / fmaxf(b1, 1e-16f);
        w3[y*3+2] = 1.0f / fmaxf(b2, 1e-16f);
    }
}

// ---------------- interpolate + concat -> X0 fp32 + Xb0 bf16 ----------------
__global__ __launch_bounds__(64) void interp_kernel(
    const float* __restrict__ x, const float* __restrict__ x_skip,
    const int* __restrict__ idx3, const float* __restrict__ w3,
    float* __restrict__ X0, __hip_bfloat16* __restrict__ Xb0)
{
    const int n = blockIdx.x, c = threadIdx.x;
    const int j0 = idx3[n*3+0], j1 = idx3[n*3+1], j2 = idx3[n*3+2];
    const float w0 = w3[n*3+0], w1 = w3[n*3+1], w2 = w3[n*3+2];
    const float inv = 1.0f / (w0 + w1 + w2);
    const float h = (w0 * x[j0*64+c] + w1 * x[j1*64+c] + w2 * x[j2*64+c]) * inv;
    const float xs = x_skip[n*64+c];
    X0[(size_t)n*128 + c]      = h;
    X0[(size_t)n*128 + 64 + c] = xs;
    Xb0[(size_t)n*128 + c]      = __float2bfloat16(h);
    Xb0[(size_t)n*128 + 64 + c] = __float2bfloat16(xs);
}

// ---------------- spline basis per edge + dst histogram ----------------
__global__ __launch_bounds__(256) void basis_kernel(
    const int* __restrict__ ei, const float* __restrict__ pos_skip,
    float* __restrict__ basis, uint2* __restrict__ wi8, int* __restrict__ cntD)
{
    const int e = blockIdx.x * 256 + threadIdx.x;
    const int src = ei[e], dst = ei[NE + e];
    float fr[3]; int lo[3];
    #pragma unroll
    for (int d = 0; d < 3; ++d) {
        float p = (pos_skip[dst*3+d] - pos_skip[src*3+d]) * 4.0f + 0.5f;
        p = fminf(fmaxf(p, 0.0f), 1.0f);
        float v = p * 4.0f;
        float l = fminf(floorf(v), 3.0f);
        fr[d] = v - l;
        lo[d] = (int)l;
    }
    unsigned int wlo = 0, whi = 0;
    #pragma unroll
    for (int s = 0; s < 8; ++s) {
        const int bit0 = s & 1, bit1 = (s >> 1) & 1, bit2 = (s >> 2) & 1;
        float b = (bit0 ? fr[0] : 1.0f - fr[0])
                * (bit1 ? fr[1] : 1.0f - fr[1])
                * (bit2 ? fr[2] : 1.0f - fr[2]);
        int w = (lo[0] + bit0) + 5 * (lo[1] + bit1) + 25 * (lo[2] + bit2);
        basis[(size_t)e*8 + s] = b;
        if (s < 4) wlo |= ((unsigned)w) << (8*s);
        else       whi |= ((unsigned)w) << (8*(s-4));
    }
    wi8[e] = make_uint2(wlo, whi);
    atomicAdd(&cntD[dst], 1);
}

// ---------------- exclusive scan over NF counts, single pass (16/thread) ----------------
__global__ __launch_bounds__(1024) void scan1_kernel(
    const int* __restrict__ cnt, int* __restrict__ offs, int* __restrict__ cursor)
{
    __shared__ int s[1024];
    const int tid = threadIdx.x;
    const int base = tid * 16;
    int v[16];
    *(int4*)&v[0]  = *(const int4*)&cnt[base];
    *(int4*)&v[4]  = *(const int4*)&cnt[base+4];
    *(int4*)&v[8]  = *(const int4*)&cnt[base+8];
    *(int4*)&v[12] = *(const int4*)&cnt[base+12];
    int tsum = 0;
    #pragma unroll
    for (int j = 0; j < 16; ++j) tsum += v[j];
    s[tid] = tsum;
    __syncthreads();
    for (int off = 1; off < 1024; off <<= 1) {
        int t = (tid >= off) ? s[tid - off] : 0;
        __syncthreads();
        s[tid] += t;
        __syncthreads();
    }
    int run = s[tid] - tsum;
    #pragma unroll
    for (int j = 0; j < 16; ++j) { offs[base+j] = run; cursor[base+j] = run; run += v[j]; }
    if (tid == 1023) offs[NF] = run;
}

// ---------------- scatter: dst-sorted edge permutation ----------------
__global__ __launch_bounds__(256) void scatter1_kernel(
    const int* __restrict__ ei, int* __restrict__ cur, int* __restrict__ perm)
{
    const int e = blockIdx.x * 256 + threadIdx.x;
    const int p = atomicAdd(&cur[ei[NE + e]], 1);
    perm[p] = e;
}

// ---------------- W prep, all 3 layers: [125][KIN][64] fp32 -> [125][64][KIN] bf16 ----------------
__global__ __launch_bounds__(256) void wprep_all_kernel(
    const float* __restrict__ W0, const float* __restrict__ W1, const float* __restrict__ W2,
    __hip_bfloat16* __restrict__ Wt0, __hip_bfloat16* __restrict__ Wt1, __hip_bfloat16* __restrict__ Wt2)
{
    const int which = blockIdx.y;
    const float* W = (which == 0) ? W0 : (which == 1 ? W1 : W2);
    __hip_bfloat16* Wt = (which == 0) ? Wt0 : (which == 1 ? Wt1 : Wt2);
    const int KIN = (which == 0) ? 128 : 64;
    __shared__ float s[128*64];
    const int kern = blockIdx.x;
    const float* Wk = W + (size_t)kern * KIN * 64;
    for (int i = threadIdx.x; i < KIN*64; i += 256) s[i] = Wk[i];
    __syncthreads();
    const int nk8 = KIN/8;
    for (int i = threadIdx.x; i < 64*nk8; i += 256) {
        const int o = i / nk8, kb = (i % nk8) * 8;
        union { short8v v; __hip_bfloat16 h[8]; } u;
        #pragma unroll
        for (int j = 0; j < 8; ++j) u.h[j] = __float2bfloat16(s[(kb+j)*64 + o]);
        *(short8v*)&Wt[((size_t)kern*64 + o)*KIN + kb] = u.v;
    }
}

// ---------------- T = Xb @ W, fp8 out (HW cvt_pk, 16-B stores) ----------------
// Hybrid grid order: mi = bid&7 (8 m-tiles round-robin across XCDs -> per-XCD
// A-tile residency), kern = (bid>>3)%125 (kern-sweep -> rows complete in L2
// before eviction -> full-page write-backs), mg = bid/1000 (16 row-groups).
template<int KIN>
__global__ __launch_bounds__(256) void gemm_fp8_kernel(
    const __hip_bfloat16* __restrict__ Xb,   // [NF][KIN] bf16
    const __hip_bfloat16* __restrict__ Wt,   // [125][64][KIN]
    unsigned char* __restrict__ T)           // [NF][TROW] fp8
{
    constexpr int BKP = KIN + 8;
    __shared__ char AsRaw[34816];            // bf16 A-staging [128][BKP] / fp32 C-tile [128][68]
    __shared__ __hip_bfloat16 Bs[64*BKP];
    __hip_bfloat16* As = (__hip_bfloat16*)AsRaw;
    const int bid  = blockIdx.x;
    const int mi   = bid & 7;
    const int kern = (bid >> 3) % 125;
    const int mg   = bid / 1000;
    const int m0   = (mg * 8 + mi) << 7;

    for (int i = threadIdx.x; i < 128*(KIN/8); i += 256) {
        const int r = i / (KIN/8), c8 = (i % (KIN/8)) * 8;
        *(short8v*)&As[r*BKP + c8] = *(const short8v*)&Xb[(size_t)(m0 + r)*KIN + c8];
    }
    const __hip_bfloat16* Wk = Wt + (size_t)kern * 64 * KIN;
    for (int i = threadIdx.x; i < 64*(KIN/8); i += 256) {
        const int r = i / (KIN/8), c8 = (i % (KIN/8)) * 8;
        *(short8v*)&Bs[r*BKP + c8] = *(const short8v*)&Wk[(size_t)r*KIN + c8];
    }
    __syncthreads();

    const int wid  = threadIdx.x >> 6;
    const int lane = threadIdx.x & 63;
    const int lr   = lane & 15;
    const int lk   = (lane >> 4) * 8;

    f32x4 acc[2][4] = {};
    #pragma unroll
    for (int ks = 0; ks < KIN/32; ++ks) {
        short8v a0 = *(const short8v*)&As[(wid*32 +      lr)*BKP + ks*32 + lk];
        short8v a1 = *(const short8v*)&As[(wid*32 + 16 + lr)*BKP + ks*32 + lk];
        #pragma unroll
        for (int n = 0; n < 4; ++n) {
            short8v b = *(const short8v*)&Bs[(n*16 + lr)*BKP + ks*32 + lk];
            acc[0][n] = __builtin_amdgcn_mfma_f32_16x16x32_bf16(a0, b, acc[0][n], 0, 0, 0);
            acc[1][n] = __builtin_amdgcn_mfma_f32_16x16x32_bf16(a1, b, acc[1][n], 0, 0, 0);
        }
    }

    // epilogue: fp32 C-tile transpose in LDS
    __syncthreads();
    float* Ct = (float*)AsRaw;
    #pragma unroll
    for (int m = 0; m < 2; ++m) {
        const int rowL = wid*32 + m*16 + (lane >> 4)*4;
        #pragma unroll
        for (int n = 0; n < 4; ++n) {
            const int colL = n*16 + lr;
            #pragma unroll
            for (int i = 0; i < 4; ++i)
                Ct[(rowL + i)*68 + colL] = acc[m][n][i];
        }
    }
    __syncthreads();
    // store: 128 rows x 4 chunks of 16 fp8 bytes; HW packed convert, 16-B stores
    #pragma unroll
    for (int u = threadIdx.x; u < 512; u += 256) {
        const int row = u >> 2, ch = (u & 3) * 16;
        const float* p = &Ct[row*68 + ch];
        const float4 f0 = *(const float4*)p;
        const float4 f1 = *(const float4*)(p + 4);
        const float4 f2 = *(const float4*)(p + 8);
        const float4 f3 = *(const float4*)(p + 12);
        int w0 = __builtin_amdgcn_cvt_pk_fp8_f32(f0.x, f0.y, 0, false);
        w0     = __builtin_amdgcn_cvt_pk_fp8_f32(f0.z, f0.w, w0, true);
        int w1 = __builtin_amdgcn_cvt_pk_fp8_f32(f1.x, f1.y, 0, false);
        w1     = __builtin_amdgcn_cvt_pk_fp8_f32(f1.z, f1.w, w1, true);
        int w2 = __builtin_amdgcn_cvt_pk_fp8_f32(f2.x, f2.y, 0, false);
        w2     = __builtin_amdgcn_cvt_pk_fp8_f32(f2.z, f2.w, w2, true);
        int w3 = __builtin_amdgcn_cvt_pk_fp8_f32(f3.x, f3.y, 0, false);
        w3     = __builtin_amdgcn_cvt_pk_fp8_f32(f3.z, f3.w, w3, true);
        *(int4*)&T[(size_t)(m0 + row)*TROW + kern*64 + ch] = make_int4(w0, w1, w2, w3);
    }
}

// ---------------- FUSED agg: per-dst fp8 tap gather + mean + root + bias + ELU (+tail) ----------------
template<int KIN>
__global__ __launch_bounds__(64) void agg_fp8_kernel(
    const unsigned char* __restrict__ T, const float* __restrict__ basis,
    const uint2* __restrict__ wi8, const int* __restrict__ permD,
    const int* __restrict__ offsD, const int* __restrict__ cntD,
    const int* __restrict__ esrc,
    const float* __restrict__ X, const float* __restrict__ root,
    const float* __restrict__ bias, float* __restrict__ Xout,
    __hip_bfloat16* __restrict__ Xbout,
    const float* __restrict__ tpos, const int* __restrict__ tbatch)
{
    const int n = blockIdx.x, c = threadIdx.x;
    float a = 0.0f;
    const int beg = offsD[n], num = cntD[n];
    auto deq = [](unsigned char b) {
        __hip_fp8_e4m3 v; v.__x = b;
        return (float)v;
    };
    for (int t = 0; t < num; ++t) {
        const int e = permD[beg + t];
        const uint2 w8 = wi8[e];
        const float4 bl = *(const float4*)(basis + (size_t)e*8);
        const float4 bh = *(const float4*)(basis + (size_t)e*8 + 4);
        const unsigned char* Trow = T + (size_t)esrc[e] * TROW + c;
        a += bl.x * deq(Trow[((w8.x      ) & 255)*64]);
        a += bl.y * deq(Trow[((w8.x >>  8) & 255)*64]);
        a += bl.z * deq(Trow[((w8.x >> 16) & 255)*64]);
        a += bl.w * deq(Trow[((w8.x >> 24) & 255)*64]);
        a += bh.x * deq(Trow[((w8.y      ) & 255)*64]);
        a += bh.y * deq(Trow[((w8.y >>  8) & 255)*64]);
        a += bh.z * deq(Trow[((w8.y >> 16) & 255)*64]);
        a += bh.w * deq(Trow[((w8.y >> 24) & 255)*64]);
    }
    const float agg = a / fmaxf((float)num, 1.0f);
    const float* xr = X + (size_t)n * KIN;
    float r = 0.0f;
    #pragma unroll 16
    for (int i = 0; i < KIN; ++i) r = fmaf(xr[i], root[i*64 + c], r);
    float o = agg + r + bias[c];
    o = (o > 0.0f) ? o : expm1f(o);
    Xout[(size_t)n*64 + c] = o;
    if (Xbout) Xbout[(size_t)n*64 + c] = __float2bfloat16(o);
    if (tpos) {   // final layer: fold tail passthrough
        if (c < 3) Xout[1048576 + n*3 + c] = tpos[n*3 + c];
        if (c == 3) ((int*)Xout)[1048576 + NF*3 + n] = tbatch[n];
    }
}

extern "C" void kernel_launch(void* const* d_in, const int* in_sizes, int n_in,
                              void* d_out, int out_size, void* d_ws, size_t ws_size,
                              hipStream_t stream)
{
    const float* x          = (const float*)d_in[0];
    const float* pos        = (const float*)d_in[1];
    const int*   batch      = (const int*)d_in[2];
    const float* x_skip     = (const float*)d_in[3];
    const float* pos_skip   = (const float*)d_in[4];
    const int*   batch_skip = (const int*)d_in[5];
    const int*   ei         = (const int*)d_in[6];
    const float* W0    = (const float*)d_in[7];
    const float* root0 = (const float*)d_in[8];
    const float* b0    = (const float*)d_in[9];
    const float* W1    = (const float*)d_in[10];
    const float* root1 = (const float*)d_in[11];
    const float* b1    = (const float*)d_in[12];
    const float* W2    = (const float*)d_in[13];
    const float* root2 = (const float*)d_in[14];
    const float* b2    = (const float*)d_in[15];

    char* wp = (char*)d_ws;
    auto carve = [&](size_t bytes) {
        char* p = wp;
        wp += (bytes + 255) & ~(size_t)255;
        return p;
    };
    float* X0    = (float*)carve((size_t)NF * 128 * 4);
    float* X1    = (float*)carve((size_t)NF * 64 * 4);
    float* X2    = (float*)carve((size_t)NF * 64 * 4);
    __hip_bfloat16* Xb0 = (__hip_bfloat16*)carve((size_t)NF * 128 * 2);
    __hip_bfloat16* Xb1 = (__hip_bfloat16*)carve((size_t)NF * 64 * 2);
    __hip_bfloat16* Xb2 = (__hip_bfloat16*)carve((size_t)NF * 64 * 2);
    __hip_bfloat16* Wt0 = (__hip_bfloat16*)carve((size_t)125 * 128 * 64 * 2);
    __hip_bfloat16* Wt1 = (__hip_bfloat16*)carve((size_t)125 * 64 * 64 * 2);
    __hip_bfloat16* Wt2 = (__hip_bfloat16*)carve((size_t)125 * 64 * 64 * 2);
    float* basis = (float*)carve((size_t)NE * 8 * 4);
    uint2* wi8   = (uint2*)carve((size_t)NE * 8);
    int*   idx3  = (int*)carve((size_t)NF * 3 * 4);
    float* w3    = (float*)carve((size_t)NF * 3 * 4);
    int* zeroBase = (int*)carve((size_t)(NCELL + 2*NF) * 4);
    int* cellCnt  = zeroBase;
    int* cntD     = zeroBase + NCELL;
    int* flags    = zeroBase + NCELL + NF;
    int*   cellOffs   = (int*)carve((size_t)(NCELL+1) * 4);
    int*   cellCursor = (int*)carve((size_t)NCELL * 4);
    int*   cellId  = (int*)carve((size_t)NC * 4);
    int*   binPts  = (int*)carve((size_t)NC * 4);
    float4* binPB  = (float4*)carve((size_t)NC * 16);
    int*   offsD   = (int*)carve((size_t)(NF+1) * 4);
    int*   curD    = (int*)carve((size_t)NF * 4);
    int*   permD   = (int*)carve((size_t)NE * 4);
    unsigned char* T = (unsigned char*)carve((size_t)NF * TROW);   // 131 MB fp8

    hipMemsetAsync(zeroBase, 0, (size_t)(NCELL + 2*NF) * 4, stream);
    // KNN via uniform grid (wave-per-query, exact + fallback)
    bin_hist_kernel<<<NC/256, 256, 0, stream>>>(pos, cellCnt, cellId);
    bin_scan_kernel<<<1, 512, 0, stream>>>(cellCnt, cellOffs, cellCursor);
    bin_scatter_kernel<<<NC/256, 256, 0, stream>>>(pos, batch, cellId, cellCursor, binPts, binPB);
    knn_wave_kernel<<<NF/4, 256, 0, stream>>>(binPB, binPts, cellOffs,
                                              pos_skip, batch_skip, idx3, w3, flags);
    knn_fallback_kernel<<<NF/4, 256, 0, stream>>>(pos, batch, pos_skip, batch_skip, flags, idx3, w3);
    interp_kernel<<<NF, 64, 0, stream>>>(x, x_skip, idx3, w3, X0, Xb0);
    // edge prep
    basis_kernel<<<NE/256, 256, 0, stream>>>(ei, pos_skip, basis, wi8, cntD);
    scan1_kernel<<<1, 1024, 0, stream>>>(cntD, offsD, curD);
    scatter1_kernel<<<NE/256, 256, 0, stream>>>(ei, curD, permD);
    wprep_all_kernel<<<dim3(125, 3), 256, 0, stream>>>(W0, W1, W2, Wt0, Wt1, Wt2);

    // layer 0 (KIN=128)
    gemm_fp8_kernel<128><<<125*128, 256, 0, stream>>>(Xb0, Wt0, T);
    agg_fp8_kernel<128><<<NF, 64, 0, stream>>>(T, basis, wi8, permD, offsD, cntD, ei,
                                               X0, root0, b0, X1, Xb1, nullptr, nullptr);
    // layer 1 (KIN=64)
    gemm_fp8_kernel<64><<<125*128, 256, 0, stream>>>(Xb1, Wt1, T);
    agg_fp8_kernel<64><<<NF, 64, 0, stream>>>(T, basis, wi8, permD, offsD, cntD, ei,
                                              X1, root1, b1, X2, Xb2, nullptr, nullptr);
    // layer 2 (KIN=64) -> d_out (+tail)
    gemm_fp8_kernel<64><<<125*128, 256, 0, stream>>>(Xb2, Wt2, T);
    agg_fp8_kernel<64><<<NF, 64, 0, stream>>>(T, basis, wi8, permD, offsD, cntD, ei,
                                              X2, root2, b2, (float*)d_out, (__hip_bfloat16*)nullptr,
                                              pos_skip, batch_skip);
}

// Round 20
// 451.099 us; speedup vs baseline: 1.1218x; 1.0364x over previous
//
#include <hip/hip_runtime.h>
#include <hip/hip_bf16.h>
#include <hip/hip_fp8.h>

#define NC 8192
#define NF 16384
#define NE 262144
#define TROW 8000   // 125*64 fp8 bytes per src row
#define GB 8
#define NCELL 512
#define CELLH 0.125f

typedef __attribute__((ext_vector_type(8))) short short8v;  // 8 bf16
typedef __attribute__((ext_vector_type(4))) float f32x4;

// ---------------- binning: histogram over coarse points ----------------
__global__ __launch_bounds__(256) void bin_hist_kernel(
    const float* __restrict__ pos, int* __restrict__ cellCnt, int* __restrict__ cellId)
{
    const int i = blockIdx.x * 256 + threadIdx.x;
    const int cx = min((int)(pos[i*3+0] * GB), GB-1);
    const int cy = min((int)(pos[i*3+1] * GB), GB-1);
    const int cz = min((int)(pos[i*3+2] * GB), GB-1);
    const int cell = (cz*GB + cy)*GB + cx;
    cellId[i] = cell;
    atomicAdd(&cellCnt[cell], 1);
}

// ---------------- binning: scan 512 cells (writes sentinel) ----------------
__global__ __launch_bounds__(512) void bin_scan_kernel(
    const int* __restrict__ cellCnt, int* __restrict__ cellOffs, int* __restrict__ cellCursor)
{
    __shared__ int s[512];
    const int tid = threadIdx.x;
    const int v = cellCnt[tid];
    s[tid] = v;
    __syncthreads();
    for (int off = 1; off < 512; off <<= 1) {
        int t = (tid >= off) ? s[tid - off] : 0;
        __syncthreads();
        s[tid] += t;
        __syncthreads();
    }
    cellOffs[tid] = s[tid] - v;
    cellCursor[tid] = s[tid] - v;
    if (tid == 511) cellOffs[512] = s[511];
}

// ---------------- binning: scatter points -> packed float4 (xyz + batch bits) ----------------
__global__ __launch_bounds__(256) void bin_scatter_kernel(
    const float* __restrict__ pos, const int* __restrict__ batch,
    const int* __restrict__ cellId, int* __restrict__ cellCursor,
    int* __restrict__ binPts, float4* __restrict__ binPB)
{
    const int i = blockIdx.x * 256 + threadIdx.x;
    const int cell = cellId[i];
    const int p = atomicAdd(&cellCursor[cell], 1);
    binPts[p] = i;
    float4 q;
    q.x = pos[i*3+0]; q.y = pos[i*3+1]; q.z = pos[i*3+2];
    q.w = __int_as_float(batch[i]);
    binPB[p] = q;
}

// ---------------- KNN: one wave per query, 9 contiguous ranges, no LDS ----------------
__global__ __launch_bounds__(256) void knn_wave_kernel(
    const float4* __restrict__ binPB, const int* __restrict__ binPts,
    const int* __restrict__ cellOffs,
    const float* __restrict__ pos_skip, const int* __restrict__ batch_skip,
    int* __restrict__ idx3, float* __restrict__ w3, int* __restrict__ flags)
{
    const int lane = threadIdx.x & 63;
    const int y = blockIdx.x * 4 + (threadIdx.x >> 6);
    const float px = pos_skip[y*3+0], py = pos_skip[y*3+1], pz = pos_skip[y*3+2];
    const int by = batch_skip[y];
    const int cx = min((int)(px * GB), GB-1);
    const int cy = min((int)(py * GB), GB-1);
    const int cz = min((int)(pz * GB), GB-1);
    const int xlo = max(cx-1,0), xhi = min(cx+1,GB-1);
    const int ylo = max(cy-1,0), yhi = min(cy+1,GB-1);
    const int zlo = max(cz-1,0), zhi = min(cz+1,GB-1);

    float b0 = INFINITY, b1 = INFINITY, b2 = INFINITY;
    int i0 = 0, i1 = 0, i2 = 0;
    auto ins = [&](float d, int gj) {
        if (d < b2) {
            if (d < b1) {
                b2 = b1; i2 = i1;
                if (d < b0) { b1 = b0; i1 = i0; b0 = d; i0 = gj; }
                else        { b1 = d;  i1 = gj; }
            } else { b2 = d; i2 = gj; }
        }
    };

    for (int zz = zlo; zz <= zhi; ++zz)
    for (int yy = ylo; yy <= yhi; ++yy) {
        const int rowb = (zz*GB + yy)*GB;
        const int b = cellOffs[rowb + xlo];
        const int e = cellOffs[rowb + xhi + 1];
        for (int p = b + lane; p < e; p += 64) {
            const float4 q = binPB[p];
            const float dx = px - q.x, dy = py - q.y, dz = pz - q.z;
            float d = dx*dx + dy*dy + dz*dz;
            if (__float_as_int(q.w) != by) d = INFINITY;
            ins(d, binPts[p]);
        }
    }
    #pragma unroll
    for (int mask = 1; mask <= 32; mask <<= 1) {
        float c0 = __shfl_xor(b0, mask), c1 = __shfl_xor(b1, mask), c2 = __shfl_xor(b2, mask);
        int   j0 = __shfl_xor(i0, mask), j1 = __shfl_xor(i1, mask), j2 = __shfl_xor(i2, mask);
        ins(c0, j0); ins(c1, j1); ins(c2, j2);
    }
    if (lane == 0) {
        float rd = 1e30f;
        if (cx > 0)    rd = fminf(rd, px - (cx-1)*CELLH);
        if (cx < GB-1) rd = fminf(rd, (cx+2)*CELLH - px);
        if (cy > 0)    rd = fminf(rd, py - (cy-1)*CELLH);
        if (cy < GB-1) rd = fminf(rd, (cy+2)*CELLH - py);
        if (cz > 0)    rd = fminf(rd, pz - (cz-1)*CELLH);
        if (cz < GB-1) rd = fminf(rd, (cz+2)*CELLH - pz);
        if (!(b2 <= rd*rd)) flags[y] = 1;
        idx3[y*3+0] = i0; idx3[y*3+1] = i1; idx3[y*3+2] = i2;
        w3[y*3+0] = 1.0f / fmaxf(b0, 1e-16f);
        w3[y*3+1] = 1.0f / fmaxf(b1, 1e-16f);
        w3[y*3+2] = 1.0f / fmaxf(b2, 1e-16f);
    }
}

// ---------------- KNN fallback: exact brute force for flagged queries ----------------
__global__ __launch_bounds__(256) void knn_fallback_kernel(
    const float* __restrict__ pos, const int* __restrict__ batch,
    const float* __restrict__ pos_skip, const int* __restrict__ batch_skip,
    const int* __restrict__ flags, int* __restrict__ idx3, float* __restrict__ w3)
{
    const int s = threadIdx.x & 63;
    const int y = blockIdx.x * 4 + (threadIdx.x >> 6);
    if (!flags[y]) return;
    const float px = pos_skip[y*3+0], py = pos_skip[y*3+1], pz = pos_skip[y*3+2];
    const int by = batch_skip[y];
    float b0 = INFINITY, b1 = INFINITY, b2 = INFINITY;
    int i0 = 0, i1 = 0, i2 = 0;
    auto ins = [&](float d, int gj) {
        if (d < b2) {
            if (d < b1) {
                b2 = b1; i2 = i1;
                if (d < b0) { b1 = b0; i1 = i0; b0 = d; i0 = gj; }
                else        { b1 = d;  i1 = gj; }
            } else { b2 = d; i2 = gj; }
        }
    };
    for (int j = s; j < NC; j += 64) {
        const float dx = px - pos[j*3+0];
        const float dy = py - pos[j*3+1];
        const float dz = pz - pos[j*3+2];
        float d = dx*dx + dy*dy + dz*dz;
        if (batch[j] != by) d = INFINITY;
        ins(d, j);
    }
    #pragma unroll
    for (int mask = 1; mask <= 32; mask <<= 1) {
        float c0 = __shfl_xor(b0, mask), c1 = __shfl_xor(b1, mask), c2 = __shfl_xor(b2, mask);
        int   j0 = __shfl_xor(i0, mask), j1 = __shfl_xor(i1, mask), j2 = __shfl_xor(i2, mask);
        ins(c0, j0); ins(c1, j1); ins(c2, j2);
    }
    if (s == 0) {
        idx3[y*3+0] = i0; idx3[y*3+1] = i1; idx3[y*3+2] = i2;
        w3[y*3+0] = 1.0f / fmaxf(b0, 1e-16f);
        w3[y*3+1] = 1.0f / fmaxf(b1, 1e-16f);
        w3[y*3+2] = 1.0f / fmaxf(b2, 1e-16f);
    }
}

// ---------------- interpolate + concat -> X0 fp32 + Xb0 bf16 ----------------
__global__ __launch_bounds__(64) void interp_kernel(
    const float* __restrict__ x, const float* __restrict__ x_skip,
    const int* __restrict__ idx3, const float* __restrict__ w3,
    float* __restrict__ X0, __hip_bfloat16* __restrict__ Xb0)
{
    const int n = blockIdx.x, c = threadIdx.x;
    const int j0 = idx3[n*3+0], j1 = idx3[n*3+1], j2 = idx3[n*3+2];
    const float w0 = w3[n*3+0], w1 = w3[n*3+1], w2 = w3[n*3+2];
    const float inv = 1.0f / (w0 + w1 + w2);
    const float h = (w0 * x[j0*64+c] + w1 * x[j1*64+c] + w2 * x[j2*64+c]) * inv;
    const float xs = x_skip[n*64+c];
    X0[(size_t)n*128 + c]      = h;
    X0[(size_t)n*128 + 64 + c] = xs;
    Xb0[(size_t)n*128 + c]      = __float2bfloat16(h);
    Xb0[(size_t)n*128 + 64 + c] = __float2bfloat16(xs);
}

// ---------------- spline basis per edge + dst histogram ----------------
__global__ __launch_bounds__(256) void basis_kernel(
    const int* __restrict__ ei, const float* __restrict__ pos_skip,
    float* __restrict__ basis, uint2* __restrict__ wi8, int* __restrict__ cntD)
{
    const int e = blockIdx.x * 256 + threadIdx.x;
    const int src = ei[e], dst = ei[NE + e];
    float fr[3]; int lo[3];
    #pragma unroll
    for (int d = 0; d < 3; ++d) {
        float p = (pos_skip[dst*3+d] - pos_skip[src*3+d]) * 4.0f + 0.5f;
        p = fminf(fmaxf(p, 0.0f), 1.0f);
        float v = p * 4.0f;
        float l = fminf(floorf(v), 3.0f);
        fr[d] = v - l;
        lo[d] = (int)l;
    }
    unsigned int wlo = 0, whi = 0;
    #pragma unroll
    for (int s = 0; s < 8; ++s) {
        const int bit0 = s & 1, bit1 = (s >> 1) & 1, bit2 = (s >> 2) & 1;
        float b = (bit0 ? fr[0] : 1.0f - fr[0])
                * (bit1 ? fr[1] : 1.0f - fr[1])
                * (bit2 ? fr[2] : 1.0f - fr[2]);
        int w = (lo[0] + bit0) + 5 * (lo[1] + bit1) + 25 * (lo[2] + bit2);
        basis[(size_t)e*8 + s] = b;
        if (s < 4) wlo |= ((unsigned)w) << (8*s);
        else       whi |= ((unsigned)w) << (8*(s-4));
    }
    wi8[e] = make_uint2(wlo, whi);
    atomicAdd(&cntD[dst], 1);
}

// ---------------- exclusive scan over NF counts, single pass (16/thread) ----------------
__global__ __launch_bounds__(1024) void scan1_kernel(
    const int* __restrict__ cnt, int* __restrict__ offs, int* __restrict__ cursor)
{
    __shared__ int s[1024];
    const int tid = threadIdx.x;
    const int base = tid * 16;
    int v[16];
    *(int4*)&v[0]  = *(const int4*)&cnt[base];
    *(int4*)&v[4]  = *(const int4*)&cnt[base+4];
    *(int4*)&v[8]  = *(const int4*)&cnt[base+8];
    *(int4*)&v[12] = *(const int4*)&cnt[base+12];
    int tsum = 0;
    #pragma unroll
    for (int j = 0; j < 16; ++j) tsum += v[j];
    s[tid] = tsum;
    __syncthreads();
    for (int off = 1; off < 1024; off <<= 1) {
        int t = (tid >= off) ? s[tid - off] : 0;
        __syncthreads();
        s[tid] += t;
        __syncthreads();
    }
    int run = s[tid] - tsum;
    #pragma unroll
    for (int j = 0; j < 16; ++j) { offs[base+j] = run; cursor[base+j] = run; run += v[j]; }
    if (tid == 1023) offs[NF] = run;
}

// ---------------- scatter: dst-sorted edge permutation ----------------
__global__ __launch_bounds__(256) void scatter1_kernel(
    const int* __restrict__ ei, int* __restrict__ cur, int* __restrict__ perm)
{
    const int e = blockIdx.x * 256 + threadIdx.x;
    const int p = atomicAdd(&cur[ei[NE + e]], 1);
    perm[p] = e;
}

// ---------------- W prep, all 3 layers: [125][KIN][64] fp32 -> [125][64][KIN] bf16 ----------------
__global__ __launch_bounds__(256) void wprep_all_kernel(
    const float* __restrict__ W0, const float* __restrict__ W1, const float* __restrict__ W2,
    __hip_bfloat16* __restrict__ Wt0, __hip_bfloat16* __restrict__ Wt1, __hip_bfloat16* __restrict__ Wt2)
{
    const int which = blockIdx.y;
    const float* W = (which == 0) ? W0 : (which == 1 ? W1 : W2);
    __hip_bfloat16* Wt = (which == 0) ? Wt0 : (which == 1 ? Wt1 : Wt2);
    const int KIN = (which == 0) ? 128 : 64;
    __shared__ float s[128*64];
    const int kern = blockIdx.x;
    const float* Wk = W + (size_t)kern * KIN * 64;
    for (int i = threadIdx.x; i < KIN*64; i += 256) s[i] = Wk[i];
    __syncthreads();
    const int nk8 = KIN/8;
    for (int i = threadIdx.x; i < 64*nk8; i += 256) {
        const int o = i / nk8, kb = (i % nk8) * 8;
        union { short8v v; __hip_bfloat16 h[8]; } u;
        #pragma unroll
        for (int j = 0; j < 8; ++j) u.h[j] = __float2bfloat16(s[(kb+j)*64 + o]);
        *(short8v*)&Wt[((size_t)kern*64 + o)*KIN + kb] = u.v;
    }
}

// ---------------- T = Xb @ W, fp8 out; low-LDS variant for occupancy ----------------
// A-fragments loaded directly from global (XCD-L2-resident via m0-fast swizzle);
// LDS = B tile + 64-row fp32 C tile (two store phases).
// LDS: KIN=128 -> 34.8 KB (4 blocks/CU); KIN=64 -> 26.6 KB (~6 blocks/CU).
template<int KIN>
__global__ __launch_bounds__(256) void gemm_fp8_kernel(
    const __hip_bfloat16* __restrict__ Xb,   // [NF][KIN] bf16
    const __hip_bfloat16* __restrict__ Wt,   // [125][64][KIN]
    unsigned char* __restrict__ T)           // [NF][TROW] fp8
{
    constexpr int BKP = KIN + 8;
    __shared__ __hip_bfloat16 Bs[64*BKP];
    __shared__ float Cs[64*68];
    const int bid  = blockIdx.x;
    const int m0   = (bid & 127) << 7;       // fast index -> per-XCD A-tile residency
    const int kern = bid >> 7;               // 0..124

    const int wid  = threadIdx.x >> 6;
    const int lane = threadIdx.x & 63;
    const int lr   = lane & 15;
    const int lk   = (lane >> 4) * 8;

    // stage B into LDS (shared by all 4 waves)
    const __hip_bfloat16* Wk = Wt + (size_t)kern * 64 * KIN;
    for (int i = threadIdx.x; i < 64*(KIN/8); i += 256) {
        const int r = i / (KIN/8), c8 = (i % (KIN/8)) * 8;
        *(short8v*)&Bs[r*BKP + c8] = *(const short8v*)&Wk[(size_t)r*KIN + c8];
    }
    // A-fragments direct from global (tile is L2-hot on this XCD)
    short8v afrag[2][KIN/32];
    #pragma unroll
    for (int m = 0; m < 2; ++m)
        #pragma unroll
        for (int ks = 0; ks < KIN/32; ++ks)
            afrag[m][ks] = *(const short8v*)&Xb[(size_t)(m0 + wid*32 + m*16 + lr)*KIN + ks*32 + lk];
    __syncthreads();

    f32x4 acc[2][4] = {};
    #pragma unroll
    for (int ks = 0; ks < KIN/32; ++ks) {
        #pragma unroll
        for (int n = 0; n < 4; ++n) {
            short8v b = *(const short8v*)&Bs[(n*16 + lr)*BKP + ks*32 + lk];
            acc[0][n] = __builtin_amdgcn_mfma_f32_16x16x32_bf16(afrag[0][ks], b, acc[0][n], 0, 0, 0);
            acc[1][n] = __builtin_amdgcn_mfma_f32_16x16x32_bf16(afrag[1][ks], b, acc[1][n], 0, 0, 0);
        }
    }

    // two store phases: rows 0..63 (waves 0,1), rows 64..127 (waves 2,3)
    #pragma unroll
    for (int ph = 0; ph < 2; ++ph) {
        __syncthreads();
        if ((wid >> 1) == ph) {
            const int lwid = wid & 1;
            #pragma unroll
            for (int m = 0; m < 2; ++m) {
                const int rowL = lwid*32 + m*16 + (lane >> 4)*4;
                #pragma unroll
                for (int n = 0; n < 4; ++n) {
                    const int colL = n*16 + lr;
                    #pragma unroll
                    for (int i = 0; i < 4; ++i)
                        Cs[(rowL + i)*68 + colL] = acc[m][n][i];
                }
            }
        }
        __syncthreads();
        // 256 threads = 64 rows x 4 chunks of 16 fp8 bytes (HW packed convert)
        {
            const int u = threadIdx.x;
            const int row = u >> 2, ch = (u & 3) * 16;
            const float* p = &Cs[row*68 + ch];
            const float4 f0 = *(const float4*)p;
            const float4 f1 = *(const float4*)(p + 4);
            const float4 f2 = *(const float4*)(p + 8);
            const float4 f3 = *(const float4*)(p + 12);
            int w0 = __builtin_amdgcn_cvt_pk_fp8_f32(f0.x, f0.y, 0, false);
            w0     = __builtin_amdgcn_cvt_pk_fp8_f32(f0.z, f0.w, w0, true);
            int w1 = __builtin_amdgcn_cvt_pk_fp8_f32(f1.x, f1.y, 0, false);
            w1     = __builtin_amdgcn_cvt_pk_fp8_f32(f1.z, f1.w, w1, true);
            int w2 = __builtin_amdgcn_cvt_pk_fp8_f32(f2.x, f2.y, 0, false);
            w2     = __builtin_amdgcn_cvt_pk_fp8_f32(f2.z, f2.w, w2, true);
            int w3 = __builtin_amdgcn_cvt_pk_fp8_f32(f3.x, f3.y, 0, false);
            w3     = __builtin_amdgcn_cvt_pk_fp8_f32(f3.z, f3.w, w3, true);
            *(int4*)&T[(size_t)(m0 + ph*64 + row)*TROW + kern*64 + ch] = make_int4(w0, w1, w2, w3);
        }
    }
}

// ---------------- FUSED agg: per-dst fp8 tap gather + mean + root + bias + ELU (+tail) ----------------
template<int KIN>
__global__ __launch_bounds__(64) void agg_fp8_kernel(
    const unsigned char* __restrict__ T, const float* __restrict__ basis,
    const uint2* __restrict__ wi8, const int* __restrict__ permD,
    const int* __restrict__ offsD, const int* __restrict__ cntD,
    const int* __restrict__ esrc,
    const float* __restrict__ X, const float* __restrict__ root,
    const float* __restrict__ bias, float* __restrict__ Xout,
    __hip_bfloat16* __restrict__ Xbout,
    const float* __restrict__ tpos, const int* __restrict__ tbatch)
{
    const int n = blockIdx.x, c = threadIdx.x;
    float a = 0.0f;
    const int beg = offsD[n], num = cntD[n];
    auto deq = [](unsigned char b) {
        __hip_fp8_e4m3 v; v.__x = b;
        return (float)v;
    };
    for (int t = 0; t < num; ++t) {
        const int e = permD[beg + t];
        const uint2 w8 = wi8[e];
        const float4 bl = *(const float4*)(basis + (size_t)e*8);
        const float4 bh = *(const float4*)(basis + (size_t)e*8 + 4);
        const unsigned char* Trow = T + (size_t)esrc[e] * TROW + c;
        a += bl.x * deq(Trow[((w8.x      ) & 255)*64]);
        a += bl.y * deq(Trow[((w8.x >>  8) & 255)*64]);
        a += bl.z * deq(Trow[((w8.x >> 16) & 255)*64]);
        a += bl.w * deq(Trow[((w8.x >> 24) & 255)*64]);
        a += bh.x * deq(Trow[((w8.y      ) & 255)*64]);
        a += bh.y * deq(Trow[((w8.y >>  8) & 255)*64]);
        a += bh.z * deq(Trow[((w8.y >> 16) & 255)*64]);
        a += bh.w * deq(Trow[((w8.y >> 24) & 255)*64]);
    }
    const float agg = a / fmaxf((float)num, 1.0f);
    const float* xr = X + (size_t)n * KIN;
    float r = 0.0f;
    #pragma unroll 16
    for (int i = 0; i < KIN; ++i) r = fmaf(xr[i], root[i*64 + c], r);
    float o = agg + r + bias[c];
    o = (o > 0.0f) ? o : expm1f(o);
    Xout[(size_t)n*64 + c] = o;
    if (Xbout) Xbout[(size_t)n*64 + c] = __float2bfloat16(o);
    if (tpos) {   // final layer: fold tail passthrough
        if (c < 3) Xout[1048576 + n*3 + c] = tpos[n*3 + c];
        if (c == 3) ((int*)Xout)[1048576 + NF*3 + n] = tbatch[n];
    }
}

extern "C" void kernel_launch(void* const* d_in, const int* in_sizes, int n_in,
                              void* d_out, int out_size, void* d_ws, size_t ws_size,
                              hipStream_t stream)
{
    const float* x          = (const float*)d_in[0];
    const float* pos        = (const float*)d_in[1];
    const int*   batch      = (const int*)d_in[2];
    const float* x_skip     = (const float*)d_in[3];
    const float* pos_skip   = (const float*)d_in[4];
    const int*   batch_skip = (const int*)d_in[5];
    const int*   ei         = (const int*)d_in[6];
    const float* W0    = (const float*)d_in[7];
    const float* root0 = (const float*)d_in[8];
    const float* b0    = (const float*)d_in[9];
    const float* W1    = (const float*)d_in[10];
    const float* root1 = (const float*)d_in[11];
    const float* b1    = (const float*)d_in[12];
    const float* W2    = (const float*)d_in[13];
    const float* root2 = (const float*)d_in[14];
    const float* b2    = (const float*)d_in[15];

    char* wp = (char*)d_ws;
    auto carve = [&](size_t bytes) {
        char* p = wp;
        wp += (bytes + 255) & ~(size_t)255;
        return p;
    };
    float* X0    = (float*)carve((size_t)NF * 128 * 4);
    float* X1    = (float*)carve((size_t)NF * 64 * 4);
    float* X2    = (float*)carve((size_t)NF * 64 * 4);
    __hip_bfloat16* Xb0 = (__hip_bfloat16*)carve((size_t)NF * 128 * 2);
    __hip_bfloat16* Xb1 = (__hip_bfloat16*)carve((size_t)NF * 64 * 2);
    __hip_bfloat16* Xb2 = (__hip_bfloat16*)carve((size_t)NF * 64 * 2);
    __hip_bfloat16* Wt0 = (__hip_bfloat16*)carve((size_t)125 * 128 * 64 * 2);
    __hip_bfloat16* Wt1 = (__hip_bfloat16*)carve((size_t)125 * 64 * 64 * 2);
    __hip_bfloat16* Wt2 = (__hip_bfloat16*)carve((size_t)125 * 64 * 64 * 2);
    float* basis = (float*)carve((size_t)NE * 8 * 4);
    uint2* wi8   = (uint2*)carve((size_t)NE * 8);
    int*   idx3  = (int*)carve((size_t)NF * 3 * 4);
    float* w3    = (float*)carve((size_t)NF * 3 * 4);
    int* zeroBase = (int*)carve((size_t)(NCELL + 2*NF) * 4);
    int* cellCnt  = zeroBase;
    int* cntD     = zeroBase + NCELL;
    int* flags    = zeroBase + NCELL + NF;
    int*   cellOffs   = (int*)carve((size_t)(NCELL+1) * 4);
    int*   cellCursor = (int*)carve((size_t)NCELL * 4);
    int*   cellId  = (int*)carve((size_t)NC * 4);
    int*   binPts  = (int*)carve((size_t)NC * 4);
    float4* binPB  = (float4*)carve((size_t)NC * 16);
    int*   offsD   = (int*)carve((size_t)(NF+1) * 4);
    int*   curD    = (int*)carve((size_t)NF * 4);
    int*   permD   = (int*)carve((size_t)NE * 4);
    unsigned char* T = (unsigned char*)carve((size_t)NF * TROW);   // 131 MB fp8

    hipMemsetAsync(zeroBase, 0, (size_t)(NCELL + 2*NF) * 4, stream);
    // KNN via uniform grid (wave-per-query, exact + fallback)
    bin_hist_kernel<<<NC/256, 256, 0, stream>>>(pos, cellCnt, cellId);
    bin_scan_kernel<<<1, 512, 0, stream>>>(cellCnt, cellOffs, cellCursor);
    bin_scatter_kernel<<<NC/256, 256, 0, stream>>>(pos, batch, cellId, cellCursor, binPts, binPB);
    knn_wave_kernel<<<NF/4, 256, 0, stream>>>(binPB, binPts, cellOffs,
                                              pos_skip, batch_skip, idx3, w3, flags);
    knn_fallback_kernel<<<NF/4, 256, 0, stream>>>(pos, batch, pos_skip, batch_skip, flags, idx3, w3);
    interp_kernel<<<NF, 64, 0, stream>>>(x, x_skip, idx3, w3, X0, Xb0);
    // edge prep
    basis_kernel<<<NE/256, 256, 0, stream>>>(ei, pos_skip, basis, wi8, cntD);
    scan1_kernel<<<1, 1024, 0, stream>>>(cntD, offsD, curD);
    scatter1_kernel<<<NE/256, 256, 0, stream>>>(ei, curD, permD);
    wprep_all_kernel<<<dim3(125, 3), 256, 0, stream>>>(W0, W1, W2, Wt0, Wt1, Wt2);

    // layer 0 (KIN=128)
    gemm_fp8_kernel<128><<<125*128, 256, 0, stream>>>(Xb0, Wt0, T);
    agg_fp8_kernel<128><<<NF, 64, 0, stream>>>(T, basis, wi8, permD, offsD, cntD, ei,
                                               X0, root0, b0, X1, Xb1, nullptr, nullptr);
    // layer 1 (KIN=64)
    gemm_fp8_kernel<64><<<125*128, 256, 0, stream>>>(Xb1, Wt1, T);
    agg_fp8_kernel<64><<<NF, 64, 0, stream>>>(T, basis, wi8, permD, offsD, cntD, ei,
                                              X1, root1, b1, X2, Xb2, nullptr, nullptr);
    // layer 2 (KIN=64) -> d_out (+tail)
    gemm_fp8_kernel<64><<<125*128, 256, 0, stream>>>(Xb2, Wt2, T);
    agg_fp8_kernel<64><<<NF, 64, 0, stream>>>(T, basis, wi8, permD, offsD, cntD, ei,
                                              X2, root2, b2, (float*)d_out, (__hip_bfloat16*)nullptr,
                                              pos_skip, batch_skip);
}